// Round 4
// baseline (815.725 us; speedup 1.0000x reference)
//
#include <hip/hip_runtime.h>
#include <stdint.h>

// ---------------------------------------------------------------------------
// AstroSymbolicEpisodicLayer  (B=4, TQ=TK=2048, D=1024, R=64, H=512)
// R7: gemm256 + sched_barrier(0) pinning (HK technique 4) and explicit
// lgkmcnt(0)+sched_barrier before MFMA clusters (rule #18). Raw s_barrier is
// NOT a compiler fence; without pins the scheduler can sink all 4 STAGE
// groups to the tile-end vmcnt, collapsing prefetch distance to ~0 (theory
// for the 16%-MfmaUtil plateau of R5/R6).
// Carries R4 folding, R5 256^2 tile + swizzled LDS, R6 schedule + XCD swizzle.
// ---------------------------------------------------------------------------

#define Bq 4
#define Tq 2048
#define Dd 1024
#define NT 8192      // B*T
#define Hh 512
#define Rr_ 64
#define FQ 1024      // packed rfft spectrum width: re(0..512) | im(1..511)

typedef unsigned short ushort_t;
typedef short s16x8 __attribute__((ext_vector_type(8)));
typedef float floatx4 __attribute__((ext_vector_type(4)));

__device__ __forceinline__ float b2f(ushort_t s) {
  unsigned u = (unsigned)s << 16;
  return __builtin_bit_cast(float, u);
}
__device__ __forceinline__ ushort_t f2b(float f) {
  unsigned u = __builtin_bit_cast(unsigned, f);
  unsigned r = (u + 0x7fffu + ((u >> 16) & 1u)) >> 16;
  return (ushort_t)r;
}

__device__ __forceinline__ void load_lds16(const void* g, void* l) {
  __builtin_amdgcn_global_load_lds((__attribute__((address_space(1))) void*)(g),
                                   (__attribute__((address_space(3))) void*)(l),
                                   16, 0, 0);
}

#define SBAR() __builtin_amdgcn_sched_barrier(0)

// bijective XCD-aware remap (m204 form). Consecutive wgid chunks land on one
// XCD -> L2-local A/B panel reuse (R3: FETCH 82->33MB on scores).
__device__ __forceinline__ void xcd_swizzle(int& bx, int& by, int& bz) {
  const int gx = gridDim.x, gy = gridDim.y, gz = gridDim.z;
  const int nwg = gx * gy * gz;
  const int orig = (bz * gy + by) * gx + bx;
  const int q = nwg >> 3, r = nwg & 7;
  const int x = orig & 7, i = orig >> 3;
  const int wg = (x < r ? x * (q + 1) : r * (q + 1) + (x - r) * q) + i;
  bx = wg % gx;
  const int t = wg / gx;
  by = t % gy;
  bz = t / gy;
}

// ---------------------------------------------------------------------------
// gemm256: C[M,N] = A[M,K] @ Bt[N,K]^T, tile 256x256, BK=64, 8 waves (2Mx4N),
// wave tile 128x64. LDS 128 KiB: [slot][A/B][khalf][256][32], chunk-rotation
// swizzle (conflict-free ds_read_b128, measured 0 conflicts).
// Schedule per K-tile t (slot sl=t&1), K >= 128 — every section pinned with
// sched_barrier(0) so the emitted order IS the written order:
//   ph0: ds_read k0(12) | stage A.k1(t+1)->sl1 | bar | lgkm0 | MFMA k0.n01 | bar
//   ph1:                  stage B.k1(t+1)->sl1 | bar |         MFMA k0.n23 | bar
//   ph2: ds_read k1(12) | stage A.k0(t+2)->sl  | bar | lgkm0 | MFMA k1.n01 | bar
//   ph3:                  stage B.k0(t+2)->sl  | bar |         MFMA k1.n23 |
//        vmcnt(4) | bar
// vmcnt ledger (2 loads/group/thread): steady-state outstanding at tile end =
// 12; vmcnt(4) retires tile t+1's 4 groups -> next tile's reads safe.
// ---------------------------------------------------------------------------
__global__ __launch_bounds__(512, 2) void gemm256(
    const ushort_t* __restrict__ A, const ushort_t* __restrict__ Bt,
    float* __restrict__ C, ushort_t* __restrict__ Cbf,
    const float* __restrict__ bias_col, const float* __restrict__ bias_row,
    const float* __restrict__ rmul, int rmulStride,
    const float* __restrict__ cmul, int cmulStride,
    const float* __restrict__ tau,
    float* __restrict__ rowsum, int rsStride, int rsMode,
    int K, int lda, int ldb, int ldc,
    long long sA, long long sB, long long sC, int flags)
{
  __shared__ __align__(16) ushort_t lds[2][2][2][256][32];

  int bx = blockIdx.x, by = blockIdx.y, bz = blockIdx.z;
  xcd_swizzle(bx, by, bz);
  const ushort_t* Ab = A + (size_t)bz * sA;
  const ushort_t* Bb = Bt + (size_t)bz * sB;
  const int tm   = by * 256;
  const int tn   = bx * 256;
  const int tid  = threadIdx.x;
  const int wave = tid >> 6;        // 0..7
  const int lane = tid & 63;
  const int wm   = wave >> 2;       // 0..1 -> A rows wm*128..+127
  const int wn   = wave & 3;        // 0..3 -> B rows wn*64..+63

  const int s_r  = lane >> 2;                       // 0..15
  const int s_cg = (((lane & 3) - (s_r >> 1)) & 3); // inverse-permuted chunk
  const int f_r  = lane & 15;
  const int f_p  = ((((lane >> 4) + (f_r >> 1)) & 3) << 3);

  const int NTILES = K >> 6;

  floatx4 acc[8][4] = {};

  // stage group g (0=A.k0, 1=B.k0, 2=A.k1, 3=B.k1) of tile tt into slot sl
#define STAGE256(tt, g, sl)                                                     \
  do {                                                                          \
    const int mat_ = (g) & 1, h_ = (g) >> 1;                                    \
    const ushort_t* src_ = mat_ ? Bb : Ab;                                      \
    const int ld_ = mat_ ? ldb : lda;                                           \
    const int tb_ = mat_ ? tn : tm;                                             \
    const int kofs_ = (tt) * 64 + h_ * 32 + s_cg * 8;                           \
    _Pragma("unroll")                                                           \
    for (int j_ = 0; j_ < 2; j_++) {                                            \
      const int slab_ = wave * 2 + j_;                                          \
      const ushort_t* gp_ = src_ + (size_t)(tb_ + slab_ * 16 + s_r) * ld_ + kofs_; \
      load_lds16(gp_, (void*)&lds[sl][mat_][h_][slab_ * 16][0]);                \
    }                                                                           \
  } while (0)

  // prologue: tile0 fully + tile1 k0 groups; vmcnt(4) -> tile0 landed
  STAGE256(0, 0, 0);
  STAGE256(0, 1, 0);
  STAGE256(0, 2, 0);
  STAGE256(0, 3, 0);
  STAGE256(1, 0, 1);
  STAGE256(1, 1, 1);
  SBAR();
  asm volatile("s_waitcnt vmcnt(4)" ::: "memory");
  SBAR();
  __builtin_amdgcn_s_barrier();

  for (int t = 0; t < NTILES; t++) {
    const int sl  = t & 1;
    const int sl1 = sl ^ 1;
    const int t1  = (t + 1 < NTILES) ? t + 1 : t;  // clamped tail (writes go to
    const int t2  = (t + 2 < NTILES) ? t + 2 : t;  // never-again-read regions)
    s16x8 a[8], b[4];

    // ---- ph0: ds_read k0 frags | stage A.k1(t+1) | MFMA k0 x n{0,1} ----
#pragma unroll
    for (int m = 0; m < 8; m++)
      a[m] = *(const s16x8*)&lds[sl][0][0][wm * 128 + m * 16 + f_r][f_p];
#pragma unroll
    for (int n = 0; n < 4; n++)
      b[n] = *(const s16x8*)&lds[sl][1][0][wn * 64 + n * 16 + f_r][f_p];
    SBAR();
    STAGE256(t1, 2, sl1);
    SBAR();
    __builtin_amdgcn_s_barrier();
    asm volatile("s_waitcnt lgkmcnt(0)" ::: "memory");
    SBAR();
    __builtin_amdgcn_s_setprio(1);
#pragma unroll
    for (int m = 0; m < 8; m++)
#pragma unroll
      for (int n = 0; n < 2; n++)
        acc[m][n] = __builtin_amdgcn_mfma_f32_16x16x32_bf16(a[m], b[n], acc[m][n], 0, 0, 0);
    __builtin_amdgcn_s_setprio(0);
    SBAR();
    __builtin_amdgcn_s_barrier();

    // ---- ph1: stage B.k1(t+1) | MFMA k0 x n{2,3} ----
    STAGE256(t1, 3, sl1);
    SBAR();
    __builtin_amdgcn_s_barrier();
    __builtin_amdgcn_s_setprio(1);
#pragma unroll
    for (int m = 0; m < 8; m++)
#pragma unroll
      for (int n = 2; n < 4; n++)
        acc[m][n] = __builtin_amdgcn_mfma_f32_16x16x32_bf16(a[m], b[n], acc[m][n], 0, 0, 0);
    __builtin_amdgcn_s_setprio(0);
    SBAR();
    __builtin_amdgcn_s_barrier();

    // ---- ph2: ds_read k1 frags | stage A.k0(t+2) into consumed region ----
#pragma unroll
    for (int m = 0; m < 8; m++)
      a[m] = *(const s16x8*)&lds[sl][0][1][wm * 128 + m * 16 + f_r][f_p];
#pragma unroll
    for (int n = 0; n < 4; n++)
      b[n] = *(const s16x8*)&lds[sl][1][1][wn * 64 + n * 16 + f_r][f_p];
    SBAR();
    STAGE256(t2, 0, sl);
    SBAR();
    __builtin_amdgcn_s_barrier();
    asm volatile("s_waitcnt lgkmcnt(0)" ::: "memory");
    SBAR();
    __builtin_amdgcn_s_setprio(1);
#pragma unroll
    for (int m = 0; m < 8; m++)
#pragma unroll
      for (int n = 0; n < 2; n++)
        acc[m][n] = __builtin_amdgcn_mfma_f32_16x16x32_bf16(a[m], b[n], acc[m][n], 0, 0, 0);
    __builtin_amdgcn_s_setprio(0);
    SBAR();
    __builtin_amdgcn_s_barrier();

    // ---- ph3: stage B.k0(t+2) | MFMA k1 x n{2,3} | vmcnt(4) ----
    STAGE256(t2, 1, sl);
    SBAR();
    __builtin_amdgcn_s_barrier();
    __builtin_amdgcn_s_setprio(1);
#pragma unroll
    for (int m = 0; m < 8; m++)
#pragma unroll
      for (int n = 2; n < 4; n++)
        acc[m][n] = __builtin_amdgcn_mfma_f32_16x16x32_bf16(a[m], b[n], acc[m][n], 0, 0, 0);
    __builtin_amdgcn_s_setprio(0);
    SBAR();
    asm volatile("s_waitcnt vmcnt(4)" ::: "memory");  // tile t+1 fully landed
    SBAR();
    __builtin_amdgcn_s_barrier();
  }
#undef STAGE256

  // ---- epilogue ----
  const float tv = tau ? tau[bz] : 0.f;
  float*   Cp  = C   ? C   + (size_t)bz * sC : nullptr;
  ushort_t* Cb = Cbf ? Cbf + (size_t)bz * sC : nullptr;
  float bcv[4], cmv[4];
#pragma unroll
  for (int n = 0; n < 4; n++) {
    const int col = tn + wn * 64 + n * 16 + (lane & 15);
    bcv[n] = bias_col ? bias_col[col] : 0.f;
    cmv[n] = cmul ? cmul[(size_t)bz * cmulStride + col] : 1.f;
  }
#pragma unroll
  for (int m = 0; m < 8; m++) {
#pragma unroll
    for (int r = 0; r < 4; r++) {
      const int row = tm + wm * 128 + m * 16 + (lane >> 4) * 4 + r;
      const float rm = rmul ? rmul[(size_t)bz * rmulStride + row] : 1.f;
      const float br = bias_row ? bias_row[row] : 0.f;
      float rsum = 0.f;
#pragma unroll
      for (int n = 0; n < 4; n++) {
        const int col = tn + wn * 64 + n * 16 + (lane & 15);
        float v;
        if (flags & 2) {
          v = acc[m][n][r] * (rm * cmv[n]) + bcv[n] + br;   // scale-then-bias
        } else {
          v = (acc[m][n][r] + bcv[n] + br) * (rm * cmv[n]);
        }
        if (flags & 1) v = fmaxf(v, 0.f);
        if (tau) { float d = 1.0f - v; v = fmaxf(1.0f - tv * 0.25f * d * d, 0.f); }
        rsum += (rsMode == 2) ? v * v : v;
        if (Cp) Cp[(size_t)row * ldc + col] = v;
        if (Cb) Cb[(size_t)row * ldc + col] = f2b(v);
      }
      if (rsMode == 1 || rsMode == 2) {
        rsum += __shfl_xor(rsum, 1);
        rsum += __shfl_xor(rsum, 2);
        rsum += __shfl_xor(rsum, 4);
        rsum += __shfl_xor(rsum, 8);
        if ((lane & 15) == 0)
          atomicAdd(&rowsum[(size_t)bz * rsStride + row], rsum);
      }
    }
  }
}

// ---------------------------------------------------------------------------
// gemm_bt: 128x128 kernel (small-grid GEMMs: RF, MLP1, MLP2) + XCD swizzle
// ---------------------------------------------------------------------------
__global__ __launch_bounds__(256) void gemm_bt(
    const ushort_t* __restrict__ A, const ushort_t* __restrict__ Bt,
    float* __restrict__ C, ushort_t* __restrict__ Cbf,
    const float* __restrict__ bias_col, const float* __restrict__ bias_row,
    const float* __restrict__ rmul, int rmulStride,
    const float* __restrict__ cmul, int cmulStride,
    const float* __restrict__ tau,
    float* __restrict__ rowsum, int rsStride, int rsMode,
    int K, int lda, int ldb, int ldc,
    long long sA, long long sB, long long sC, int flags)
{
  __shared__ __align__(16) ushort_t As[128 * 32];
  __shared__ __align__(16) ushort_t Bs[128 * 32];

  int bx = blockIdx.x, by = blockIdx.y, bz = blockIdx.z;
  xcd_swizzle(bx, by, bz);
  const ushort_t* Ab = A + (size_t)bz * sA;
  const ushort_t* Bb = Bt + (size_t)bz * sB;
  const int tm   = by * 128;
  const int tn   = bx * 128;
  const int tid  = threadIdx.x;
  const int wave = tid >> 6;
  const int lane = tid & 63;
  const int wm   = (wave & 1) << 6;
  const int wn   = (wave >> 1) << 6;
  const int sr   = lane >> 2;
  const int cp   = lane & 3;
  const int sc   = (((cp - (sr >> 1)) & 3) << 3);
  const int fr   = lane & 15;
  const int fk   = ((((lane >> 4) + (fr >> 1)) & 3) << 3);

  floatx4 acc[4][4] = {};

  for (int k0 = 0; k0 < K; k0 += 32) {
    {
      const ushort_t* gA0 = Ab + (size_t)(tm + wave * 16 + sr) * lda + (k0 + sc);
      const ushort_t* gA1 = gA0 + (size_t)64 * lda;
      char* lA = (char*)As + wave * 1024;
      load_lds16(gA0, lA);
      load_lds16(gA1, lA + 4096);
      const ushort_t* gB0 = Bb + (size_t)(tn + wave * 16 + sr) * ldb + (k0 + sc);
      const ushort_t* gB1 = gB0 + (size_t)64 * ldb;
      char* lB = (char*)Bs + wave * 1024;
      load_lds16(gB0, lB);
      load_lds16(gB1, lB + 4096);
    }
    __syncthreads();
    s16x8 af[4], bfv[4];
#pragma unroll
    for (int i = 0; i < 4; i++)
      af[i] = *(const s16x8*)&As[(wm + i * 16 + fr) * 32 + fk];
#pragma unroll
    for (int j = 0; j < 4; j++)
      bfv[j] = *(const s16x8*)&Bs[(wn + j * 16 + fr) * 32 + fk];
#pragma unroll
    for (int i = 0; i < 4; i++)
#pragma unroll
      for (int j = 0; j < 4; j++)
        acc[i][j] = __builtin_amdgcn_mfma_f32_16x16x32_bf16(af[i], bfv[j], acc[i][j], 0, 0, 0);
    __syncthreads();
  }

  const float tv = tau ? tau[bz] : 0.f;
  float*   Cp  = C   ? C   + (size_t)bz * sC : nullptr;
  ushort_t* Cb = Cbf ? Cbf + (size_t)bz * sC : nullptr;
  float bcv[4], cmv[4];
#pragma unroll
  for (int j = 0; j < 4; j++) {
    const int col = tn + wn + j * 16 + (lane & 15);
    bcv[j] = bias_col ? bias_col[col] : 0.f;
    cmv[j] = cmul ? cmul[(size_t)bz * cmulStride + col] : 1.f;
  }
#pragma unroll
  for (int i = 0; i < 4; i++) {
#pragma unroll
    for (int r = 0; r < 4; r++) {
      const int row = tm + wm + i * 16 + (lane >> 4) * 4 + r;
      const float rm = rmul ? rmul[(size_t)bz * rmulStride + row] : 1.f;
      const float br = bias_row ? bias_row[row] : 0.f;
      float rsum = 0.f;
#pragma unroll
      for (int j = 0; j < 4; j++) {
        const int col = tn + wn + j * 16 + (lane & 15);
        float v;
        if (flags & 2) {
          v = acc[i][j][r] * (rm * cmv[j]) + bcv[j] + br;
        } else {
          v = (acc[i][j][r] + bcv[j] + br) * (rm * cmv[j]);
        }
        if (flags & 1) v = fmaxf(v, 0.f);
        if (tau) { float d = 1.0f - v; v = fmaxf(1.0f - tv * 0.25f * d * d, 0.f); }
        rsum += (rsMode == 2) ? v * v : v;
        if (Cp) Cp[(size_t)row * ldc + col] = v;
        if (Cb) Cb[(size_t)row * ldc + col] = f2b(v);
      }
      if (rsMode == 1 || rsMode == 2) {
        rsum += __shfl_xor(rsum, 1);
        rsum += __shfl_xor(rsum, 2);
        rsum += __shfl_xor(rsum, 4);
        rsum += __shfl_xor(rsum, 8);
        if ((lane & 15) == 0)
          atomicAdd(&rowsum[(size_t)bz * rsStride + row], rsum);
      }
    }
  }
}

// ---------------------------------------------------------------------------
// prep3: batched weight-product GEMMs (K=1024, bf16 out)
// ---------------------------------------------------------------------------
struct P3 { const ushort_t* A[3]; const ushort_t* Bt[3]; ushort_t* C[3]; int M[3]; };

__global__ __launch_bounds__(256) void prep3(P3 p) {
  __shared__ __align__(16) ushort_t As[128 * 32];
  __shared__ __align__(16) ushort_t Bs[128 * 32];
  const int z  = blockIdx.z;
  const int tm = blockIdx.y * 128;
  if (tm >= p.M[z]) return;
  const ushort_t* Ab = p.A[z];
  const ushort_t* Bb = p.Bt[z];
  ushort_t*       Cc = p.C[z];
  const int tn   = blockIdx.x * 128;
  const int tid  = threadIdx.x;
  const int wave = tid >> 6;
  const int lane = tid & 63;
  const int wm   = (wave & 1) << 6;
  const int wn   = (wave >> 1) << 6;
  const int sr   = lane >> 2;
  const int cp   = lane & 3;
  const int sc   = (((cp - (sr >> 1)) & 3) << 3);
  const int fr   = lane & 15;
  const int fk   = ((((lane >> 4) + (fr >> 1)) & 3) << 3);

  floatx4 acc[4][4] = {};

  for (int k0 = 0; k0 < Dd; k0 += 32) {
    {
      const ushort_t* gA0 = Ab + (size_t)(tm + wave * 16 + sr) * Dd + (k0 + sc);
      const ushort_t* gA1 = gA0 + (size_t)64 * Dd;
      char* lA = (char*)As + wave * 1024;
      load_lds16(gA0, lA);
      load_lds16(gA1, lA + 4096);
      const ushort_t* gB0 = Bb + (size_t)(tn + wave * 16 + sr) * Dd + (k0 + sc);
      const ushort_t* gB1 = gB0 + (size_t)64 * Dd;
      char* lB = (char*)Bs + wave * 1024;
      load_lds16(gB0, lB);
      load_lds16(gB1, lB + 4096);
    }
    __syncthreads();
    s16x8 af[4], bfv[4];
#pragma unroll
    for (int i = 0; i < 4; i++)
      af[i] = *(const s16x8*)&As[(wm + i * 16 + fr) * 32 + fk];
#pragma unroll
    for (int j = 0; j < 4; j++)
      bfv[j] = *(const s16x8*)&Bs[(wn + j * 16 + fr) * 32 + fk];
#pragma unroll
    for (int i = 0; i < 4; i++)
#pragma unroll
      for (int j = 0; j < 4; j++)
        acc[i][j] = __builtin_amdgcn_mfma_f32_16x16x32_bf16(af[i], bfv[j], acc[i][j], 0, 0, 0);
    __syncthreads();
  }

#pragma unroll
  for (int i = 0; i < 4; i++)
#pragma unroll
    for (int r = 0; r < 4; r++) {
      const int row = tm + wm + i * 16 + (lane >> 4) * 4 + r;
#pragma unroll
      for (int j = 0; j < 4; j++) {
        const int col = tn + wn + j * 16 + (lane & 15);
        Cc[(size_t)row * Dd + col] = f2b(acc[i][j][r]);
      }
    }
}

// ---------------------------------------------------------------------------
// small kernels
// ---------------------------------------------------------------------------
__global__ __launch_bounds__(256) void castbf(const float* __restrict__ in,
                                              ushort_t* __restrict__ out, int n4) {
  int i = blockIdx.x * 256 + threadIdx.x;
  if (i >= n4) return;
  float4 v = ((const float4*)in)[i];
  ushort4 o;
  o.x = f2b(v.x); o.y = f2b(v.y); o.z = f2b(v.z); o.w = f2b(v.w);
  ((ushort4*)out)[i] = o;
}

struct TC4 { const float* in[4]; ushort_t* out[4]; };
__global__ __launch_bounds__(256) void tcast4(TC4 p) {
  __shared__ float t[32][33];
  int z = blockIdx.z;
  const float* in = p.in[z];
  ushort_t* out = p.out[z];
  int r0 = blockIdx.x * 32, c0 = blockIdx.y * 32;
  int x = threadIdx.x, y = threadIdx.y;
  for (int dy = 0; dy < 32; dy += 8)
    t[y + dy][x] = in[(size_t)(r0 + y + dy) * 1024 + c0 + x];
  __syncthreads();
  for (int dy = 0; dy < 32; dy += 8)
    out[(size_t)(c0 + y + dy) * 1024 + r0 + x] = f2b(t[x][y + dy]);
}

__global__ __launch_bounds__(256) void tcast(const float* __restrict__ in,
                                             ushort_t* __restrict__ out,
                                             int RrN, int Cc, int Cp) {
  __shared__ float t[32][33];
  int r0 = blockIdx.x * 32, c0 = blockIdx.y * 32;
  int x = threadIdx.x, y = threadIdx.y;
  for (int dy = 0; dy < 32; dy += 8) {
    int r = r0 + y + dy, c = c0 + x;
    t[y + dy][x] = (c < Cc) ? in[(size_t)r * Cc + c] : 0.f;
  }
  __syncthreads();
  for (int dy = 0; dy < 32; dy += 8) {
    int c = c0 + y + dy, r = r0 + x;
    if (c < Cp) out[(size_t)c * RrN + r] = f2b(t[x][y + dy]);
  }
}

__global__ __launch_bounds__(256) void rolenorm(const float* __restrict__ rm,
                                                ushort_t* __restrict__ rmn) {
  int r = blockIdx.x, tid = threadIdx.x;
  float4 v = ((const float4*)(rm + (size_t)r * 1024))[tid];
  float s = v.x * v.x + v.y * v.y + v.z * v.z + v.w * v.w;
#pragma unroll
  for (int m = 1; m < 64; m <<= 1) s += __shfl_xor(s, m);
  __shared__ float red[6];
  if ((tid & 63) == 0) red[tid >> 6] = s;
  __syncthreads();
  if (tid == 0) red[4] = 1.f / fmaxf(sqrtf(red[0] + red[1] + red[2] + red[3]), 1e-12f);
  __syncthreads();
  float inv = red[4];
  ushort4 o;
  o.x = f2b(v.x * inv); o.y = f2b(v.y * inv); o.z = f2b(v.z * inv); o.w = f2b(v.w * inv);
  ((ushort4*)(rmn + (size_t)r * 1024))[tid] = o;
}

__global__ __launch_bounds__(256) void rfn_kernel(const ushort_t* __restrict__ rmn,
                                                  const ushort_t* __restrict__ ftab,
                                                  ushort_t* __restrict__ RFnT) {
  int f = blockIdx.x;
  int t = threadIdx.x;
  int r = t >> 2, part = t & 3;
  const ushort_t* fr = ftab + (size_t)f * 1024 + part * 256;
  const ushort_t* rr = rmn + (size_t)r * 1024 + part * 256;
  float s = 0.f;
#pragma unroll 4
  for (int i = 0; i < 32; i++) {
    s16x8 a = *(const s16x8*)(fr + i * 8);
    s16x8 b = *(const s16x8*)(rr + i * 8);
#pragma unroll
    for (int j = 0; j < 8; j++) s += b2f((ushort_t)a[j]) * b2f((ushort_t)b[j]);
  }
  s += __shfl_xor(s, 1);
  s += __shfl_xor(s, 2);
  if (part == 0) RFnT[(size_t)f * 128 + r] = f2b(s);
}

__global__ __launch_bounds__(64) void foldbk(const ushort_t* __restrict__ ftab,
                                             const float* __restrict__ bk,
                                             float* __restrict__ bkF) {
  int j = blockIdx.x, lane = threadIdx.x;
  const ushort_t* row = ftab + (size_t)j * 1024 + lane * 16;
  const float* bp = bk + lane * 16;
  float s = 0.f;
#pragma unroll
  for (int i = 0; i < 2; i++) {
    s16x8 a = *(const s16x8*)(row + i * 8);
#pragma unroll
    for (int e = 0; e < 8; e++) s += b2f((ushort_t)a[e]) * bp[i * 8 + e];
  }
#pragma unroll
  for (int m = 1; m < 64; m <<= 1) s += __shfl_xor(s, m);
  if (lane == 0) bkF[j] = s;
}

__global__ __launch_bounds__(256) void foldbh(const float* __restrict__ Wr1,
                                              const float* __restrict__ bk,
                                              const float* __restrict__ br1,
                                              float* __restrict__ bh) {
  int h = blockIdx.x * 256 + threadIdx.x;
  float s = br1[h];
  for (int d = 0; d < 1024; d++) s += bk[d] * Wr1[(size_t)d * Hh + h];
  bh[h] = s;
}

__global__ __launch_bounds__(256) void foldbvo(const float* __restrict__ Wo,
                                               const float* __restrict__ bv,
                                               const float* __restrict__ bo,
                                               float* __restrict__ bvo) {
  int d = blockIdx.x * 256 + threadIdx.x;
  float s = bo[d];
  for (int e = 0; e < 1024; e++) s += bv[e] * Wo[(size_t)e * 1024 + d];
  bvo[d] = s;
}

__global__ __launch_bounds__(256) void invnorm_surprise(const float* __restrict__ ssq,
                                                        float* __restrict__ invn,
                                                        float* __restrict__ ssum) {
  int row = blockIdx.x * 256 + threadIdx.x;
  float nrm = sqrtf(ssq[row]);
  invn[row] = 1.f / fmaxf(nrm, 1e-12f);
  float t = nrm;
#pragma unroll
  for (int m = 1; m < 64; m <<= 1) t += __shfl_xor(t, m);
  if ((threadIdx.x & 63) == 0) atomicAdd(&ssum[row >> 11], t);
}

__global__ __launch_bounds__(256) void invnorm(const float* __restrict__ ssq,
                                               float* __restrict__ invn) {
  int row = blockIdx.x * 256 + threadIdx.x;
  invn[row] = 1.f / fmaxf(sqrtf(ssq[row]), 1e-12f);
}

__global__ __launch_bounds__(256) void invrowsum(const float* __restrict__ rs,
                                                 float* __restrict__ inv) {
  int row = blockIdx.x * 256 + threadIdx.x;
  inv[row] = 1.f / fmaxf(rs[row], 1e-9f);
}

__global__ void finalize_astro(const float* __restrict__ ssum, const float* __restrict__ astro,
                               const float* __restrict__ ascale, float* __restrict__ tau,
                               float* __restrict__ outTail) {
  int b = threadIdx.x;
  if (b < Bq) {
    float mean = ssum[b] * (1.f / (32.f * 2048.f));
    float ns = 0.95f * astro[b] + 0.05f * mean;
    tau[b] = fmaxf(1.f + ascale[0] * ns, 0.001f);
    outTail[b] = ns;
  }
}

__global__ __launch_bounds__(256) void softmax64(const float* __restrict__ logits,
                                                 ushort_t* __restrict__ out) {
  int row = blockIdx.x * 4 + (threadIdx.x >> 6);
  int lane = threadIdx.x & 63;
  float x = logits[(size_t)row * 128 + lane];
  float m = x;
#pragma unroll
  for (int s = 1; s < 64; s <<= 1) m = fmaxf(m, __shfl_xor(m, s));
  float e = expf(x - m);
  float sum = e;
#pragma unroll
  for (int s = 1; s < 64; s <<= 1) sum += __shfl_xor(sum, s);
  out[(size_t)row * 64 + lane] = f2b(e / sum);
}

__global__ __launch_bounds__(256) void gen_ftab(ushort_t* __restrict__ ftab) {
  const float TW = 6.283185307179586f / 1024.f;
  int idx = blockIdx.x * 256 + threadIdx.x;
  int j = idx >> 10, k = idx & 1023;
  int f = j <= 512 ? j : j - 512;
  float th = (float)((f * k) & 1023) * TW;
  float sv, cv; sincosf(th, &sv, &cv);
  ftab[idx] = f2b(j <= 512 ? cv : -sv);
}

__global__ __launch_bounds__(256) void gen_itab(ushort_t* __restrict__ itab) {
  const float TW = 6.283185307179586f / 1024.f;
  int idx = blockIdx.x * 256 + threadIdx.x;
  int n = idx >> 10, j = idx & 1023;
  float v;
  if (j <= 512) {
    float w = (j == 0 || j == 512) ? (1.f / 1024.f) : (2.f / 1024.f);
    float th = (float)((j * n) & 1023) * TW;
    float sv, cv; sincosf(th, &sv, &cv);
    v = w * cv;
  } else {
    int f = j - 512;
    float th = (float)((f * n) & 1023) * TW;
    float sv, cv; sincosf(th, &sv, &cv);
    v = -(2.f / 1024.f) * sv;
  }
  itab[idx] = f2b(v);
}

__global__ __launch_bounds__(256) void fftmul(const ushort_t* __restrict__ KF,
                                              const ushort_t* __restrict__ RF,
                                              ushort_t* __restrict__ P) {
  int idx = blockIdx.x * 256 + threadIdx.x;
  int t = idx >> 9;
  int j = idx & 511;
  size_t base = (size_t)t * FQ;
  if (j == 0) {
    P[base]       = f2b(b2f(KF[base]) * b2f(RF[base]));
    P[base + 512] = f2b(b2f(KF[base + 512]) * b2f(RF[base + 512]));
  } else {
    float a = b2f(KF[base + j]), b = b2f(KF[base + 512 + j]);
    float c = b2f(RF[base + j]), d = b2f(RF[base + 512 + j]);
    P[base + j]       = f2b(a * c - b * d);
    P[base + 512 + j] = f2b(a * d + b * c);
  }
}

// ---------------------------------------------------------------------------
// workspace layout (bytes, 256-aligned)
// ---------------------------------------------------------------------------
static constexpr size_t OFF_RS    = 0;
static constexpr size_t OFF_SSQQ  = 32768;
static constexpr size_t OFF_SSQK  = 65536;
static constexpr size_t OFF_INVQ  = 98304;
static constexpr size_t OFF_INVK  = 131072;
static constexpr size_t OFF_INVRS = 163840;
static constexpr size_t OFF_SSUM  = 196608;
static constexpr size_t OFF_TAU   = 196864;
static constexpr size_t OFF_WQT   = 197120;
static constexpr size_t OFF_WKB   = OFF_WQT  + 2097152;
static constexpr size_t OFF_WVB   = OFF_WKB  + 2097152;
static constexpr size_t OFF_WOT   = OFF_WVB  + 2097152;
static constexpr size_t OFF_WR1T  = OFF_WOT  + 2097152;
static constexpr size_t OFF_WR2T  = OFF_WR1T + 1048576;
static constexpr size_t OFF_RMN   = OFF_WR2T + 131072;
static constexpr size_t OFF_FTAB  = OFF_RMN  + 131072;
static constexpr size_t OFF_ITAB  = OFF_FTAB + 2097152;
static constexpr size_t OFF_RFNT  = OFF_ITAB + 2097152;
static constexpr size_t OFF_B1    = OFF_RFNT + 262144;
static constexpr size_t OFF_B2    = OFF_B1   + 16777216;
static constexpr size_t OFF_B3    = OFF_B2   + 16777216;
static constexpr size_t OFF_B4    = OFF_B3   + 16777216;
static constexpr size_t OFF_B5    = OFF_B4   + 16777216;
static constexpr size_t OFF_B6    = OFF_B5   + 16777216;
static constexpr size_t OFF_B7    = OFF_B6   + 16777216;
static constexpr size_t OFF_HID   = OFF_B7   + 16777216;
static constexpr size_t OFF_LOGI  = OFF_HID  + 8388608;
static constexpr size_t OFF_RW    = OFF_LOGI + 4194304;
static constexpr size_t OFF_SB    = OFF_RW   + 1048576;
static constexpr size_t WS_NEEDED = OFF_SB   + 33554432;
static constexpr size_t OFF_WKF   = OFF_B6;
static constexpr size_t OFF_WOV   = OFF_B6 + 2097152;
static constexpr size_t OFF_WKR1  = OFF_B6 + 4194304;
static constexpr size_t OFF_BKF   = OFF_B6 + 5242880;
static constexpr size_t OFF_BH    = OFF_B6 + 5247232;
static constexpr size_t OFF_BVO   = OFF_B6 + 5249536;

static inline void launch_gemm(hipStream_t s, const ushort_t* A, const ushort_t* Bt,
                               float* Cf, ushort_t* Cb,
                               const float* bias_col, const float* bias_row,
                               const float* rmul, int rmulStride,
                               const float* cmul, int cmulStride,
                               const float* tau, float* rowsum, int rsStride, int rsMode,
                               int M, int N, int K, int lda, int ldb, int ldc,
                               long long sA, long long sB, long long sC, int Z, int flags) {
  dim3 g(N / 128, M / 128, Z), b(256);
  gemm_bt<<<g, b, 0, s>>>(A, Bt, Cf, Cb, bias_col, bias_row, rmul, rmulStride,
                          cmul, cmulStride, tau, rowsum, rsStride, rsMode,
                          K, lda, ldb, ldc, sA, sB, sC, flags);
}

static inline void launch_gemm256(hipStream_t s, const ushort_t* A, const ushort_t* Bt,
                                  float* Cf, ushort_t* Cb,
                                  const float* bias_col, const float* bias_row,
                                  const float* rmul, int rmulStride,
                                  const float* cmul, int cmulStride,
                                  const float* tau, float* rowsum, int rsStride, int rsMode,
                                  int M, int N, int K, int lda, int ldb, int ldc,
                                  long long sA, long long sB, long long sC, int Z, int flags) {
  dim3 g(N / 256, M / 256, Z), b(512);
  gemm256<<<g, b, 0, s>>>(A, Bt, Cf, Cb, bias_col, bias_row, rmul, rmulStride,
                          cmul, cmulStride, tau, rowsum, rsStride, rsMode,
                          K, lda, ldb, ldc, sA, sB, sC, flags);
}

extern "C" void kernel_launch(void* const* d_in, const int* in_sizes, int n_in,
                              void* d_out, int out_size, void* d_ws, size_t ws_size,
                              hipStream_t stream) {
  (void)in_sizes; (void)n_in; (void)out_size;
  if (ws_size < WS_NEEDED) return;

  const float* q_in  = (const float*)d_in[0];
  const float* k_in  = (const float*)d_in[1];
  const float* v_in  = (const float*)d_in[2];
  const float* astro = (const float*)d_in[3];
  const float* Wq    = (const float*)d_in[4];
  const float* bq    = (const float*)d_in[5];
  const float* Wk    = (const float*)d_in[6];
  const float* bk    = (const float*)d_in[7];
  const float* Wv    = (const float*)d_in[8];
  const float* bv    = (const float*)d_in[9];
  const float* Wo    = (const float*)d_in[10];
  const float* bo    = (const float*)d_in[11];
  const float* roleM = (const float*)d_in[12];
  const float* Wr1   = (const float*)d_in[13];
  const float* br1   = (const float*)d_in[14];
  const float* Wr2   = (const float*)d_in[15];
  const float* ascl  = (const float*)d_in[16];

  char* ws = (char*)d_ws;
  float*    rowsumS = (float*)(ws + OFF_RS);
  float*    ssqQ    = (float*)(ws + OFF_SSQQ);
  float*    ssqK    = (float*)(ws + OFF_SSQK);
  float*    invQ    = (float*)(ws + OFF_INVQ);
  float*    invK    = (float*)(ws + OFF_INVK);
  float*    invRS   = (float*)(ws + OFF_INVRS);
  float*    ssum    = (float*)(ws + OFF_SSUM);
  float*    tau     = (float*)(ws + OFF_TAU);
  ushort_t* WqT  = (ushort_t*)(ws + OFF_WQT);
  ushort_t* Wkb  = (ushort_t*)(ws + OFF_WKB);
  ushort_t* Wvb  = (ushort_t*)(ws + OFF_WVB);
  ushort_t* WoT  = (ushort_t*)(ws + OFF_WOT);
  ushort_t* Wr1T = (ushort_t*)(ws + OFF_WR1T);
  ushort_t* Wr2T = (ushort_t*)(ws + OFF_WR2T);
  ushort_t* rmn  = (ushort_t*)(ws + OFF_RMN);
  ushort_t* FTab = (ushort_t*)(ws + OFF_FTAB);
  ushort_t* ITab = (ushort_t*)(ws + OFF_ITAB);
  ushort_t* RFnT = (ushort_t*)(ws + OFF_RFNT);
  ushort_t* qbf  = (ushort_t*)(ws + OFF_B1);
  ushort_t* KF   = (ushort_t*)(ws + OFF_B1);
  ushort_t* kinb = (ushort_t*)(ws + OFF_B2);
  ushort_t* RF   = (ushort_t*)(ws + OFF_B2);
  ushort_t* vinb = (ushort_t*)(ws + OFF_B3);
  ushort_t* Pb   = (ushort_t*)(ws + OFF_B3);
  ushort_t* qraw = (ushort_t*)(ws + OFF_B4);
  ushort_t* kbraw= (ushort_t*)(ws + OFF_B5);
  ushort_t* WkF  = (ushort_t*)(ws + OFF_WKF);
  ushort_t* Wov  = (ushort_t*)(ws + OFF_WOV);
  ushort_t* WkR1 = (ushort_t*)(ws + OFF_WKR1);
  float*    bkF  = (float*)(ws + OFF_BKF);
  float*    bh   = (float*)(ws + OFF_BH);
  float*    bvo  = (float*)(ws + OFF_BVO);
  ushort_t* vT   = (ushort_t*)(ws + OFF_B7);
  ushort_t* hid  = (ushort_t*)(ws + OFF_HID);
  float*    logi = (float*)(ws + OFF_LOGI);
  ushort_t* rw   = (ushort_t*)(ws + OFF_RW);
  ushort_t* Sb   = (ushort_t*)(ws + OFF_SB);
  float*    out  = (float*)d_out;

  // 0. zero accumulators
  hipMemsetAsync(ws, 0, OFF_SSUM + 256, stream);

  // 1. weight prep + tables
  TC4 tc4;
  tc4.in[0] = Wq; tc4.out[0] = WqT;
  tc4.in[1] = Wo; tc4.out[1] = WoT;
  tc4.in[2] = Wq; tc4.out[2] = WqT;
  tc4.in[3] = Wq; tc4.out[3] = WqT;
  tcast4<<<dim3(32, 32, 2), dim3(32, 8), 0, stream>>>(tc4);
  castbf<<<1024, 256, 0, stream>>>(Wk, Wkb, 262144);
  castbf<<<1024, 256, 0, stream>>>(Wv, Wvb, 262144);
  tcast<<<dim3(32, 16), dim3(32, 8), 0, stream>>>(Wr1, Wr1T, 1024, 512, 512);
  tcast<<<dim3(16, 4),  dim3(32, 8), 0, stream>>>(Wr2, Wr2T, 512, 64, 128);
  rolenorm<<<64, 256, 0, stream>>>(roleM, rmn);
  gen_ftab<<<(FQ * 1024) / 256, 256, 0, stream>>>(FTab);
  gen_itab<<<(1024 * FQ) / 256, 256, 0, stream>>>(ITab);
  rfn_kernel<<<FQ, 256, 0, stream>>>(rmn, FTab, RFnT);

  P3 p3;
  p3.A[0] = FTab; p3.Bt[0] = Wkb; p3.C[0] = WkF;  p3.M[0] = 1024;
  p3.A[1] = WoT;  p3.Bt[1] = Wvb; p3.C[1] = Wov;  p3.M[1] = 1024;
  p3.A[2] = Wr1T; p3.Bt[2] = Wkb; p3.C[2] = WkR1; p3.M[2] = 512;
  prep3<<<dim3(8, 8, 3), 256, 0, stream>>>(p3);
  foldbk<<<1024, 64, 0, stream>>>(FTab, bk, bkF);
  foldbh<<<Hh / 256, 256, 0, stream>>>(Wr1, bk, br1, bh);
  foldbvo<<<Dd / 256, 256, 0, stream>>>(Wo, bv, bo, bvo);

  // 2. Q path
  castbf<<<8192, 256, 0, stream>>>(q_in, qbf, NT * Dd / 4);
  launch_gemm256(stream, qbf, WqT, nullptr, qraw, bq, nullptr,
                 nullptr, 0, nullptr, 0, nullptr, ssqQ, 0, 2,
                 NT, Dd, Dd, Dd, Dd, Dd, 0, 0, 0, 1, 0);
  invnorm_surprise<<<NT / 256, 256, 0, stream>>>(ssqQ, invQ, ssum);
  finalize_astro<<<1, 64, 0, stream>>>(ssum, astro, ascl, tau, out + (size_t)NT * Dd);

  // 3. role path (K-proj folded away)
  castbf<<<8192, 256, 0, stream>>>(k_in, kinb, NT * Dd / 4);
  launch_gemm(stream, kinb, WkR1, nullptr, hid, bh, nullptr,
              nullptr, 0, nullptr, 0, nullptr, nullptr, 0, 0,
              NT, Hh, Dd, Dd, Dd, Hh, 0, 0, 0, 1, 1 /*relu*/);
  launch_gemm(stream, hid, Wr2T, logi, nullptr, nullptr, nullptr,
              nullptr, 0, nullptr, 0, nullptr, nullptr, 0, 0,
              NT, 128, Hh, Hh, Hh, 128, 0, 0, 0, 1, 0);
  softmax64<<<NT / 4, 256, 0, stream>>>(logi, rw);

  // 4. binding forward transforms
  launch_gemm256(stream, kinb, WkF, nullptr, KF, bkF, nullptr,
                 nullptr, 0, nullptr, 0, nullptr, nullptr, 0, 0,
                 NT, FQ, Dd, Dd, Dd, FQ, 0, 0, 0, 1, 0);
  launch_gemm(stream, rw, RFnT, nullptr, RF, nullptr, nullptr,
              nullptr, 0, nullptr, 0, nullptr, nullptr, 0, 0,
              NT, FQ, Rr_, Rr_, 128, FQ, 0, 0, 0, 1, 0);

  // 5. V path (Wo folded in)
  castbf<<<8192, 256, 0, stream>>>(v_in, vinb, NT * Dd / 4);
  launch_gemm256(stream, Wov, vinb, nullptr, vT, nullptr, nullptr,
                 nullptr, 0, nullptr, 0, nullptr, nullptr, 0, 0,
                 Dd, NT, Dd, Dd, Dd, NT, 0, 0, 0, 1, 0);

  // 6. pointwise bind + inverse DFT (+sumsq)
  fftmul<<<(NT * 512) / 256, 256, 0, stream>>>(KF, RF, Pb);
  launch_gemm256(stream, Pb, ITab, nullptr, kbraw, nullptr, nullptr,
                 nullptr, 0, nullptr, 0, nullptr, ssqK, 0, 2,
                 NT, Dd, FQ, FQ, FQ, Dd, 0, 0, 0, 1, 0);
  invnorm<<<NT / 256, 256, 0, stream>>>(ssqK, invK);

  // 7. attention
  launch_gemm256(stream, qraw, kbraw, nullptr, Sb, nullptr, nullptr,
                 invQ, Tq, invK, Tq, tau, rowsumS, Tq, 1,
                 Tq, Tq, Dd, Dd, Dd, Tq,
                 (long long)Tq * Dd, (long long)Tq * Dd, (long long)Tq * Tq, Bq, 0);
  invrowsum<<<NT / 256, 256, 0, stream>>>(rowsumS, invRS);
  launch_gemm256(stream, Sb, vT, out, nullptr, bvo, nullptr,
                 invRS, Tq, nullptr, 0, nullptr, nullptr, 0, 0,
                 Tq, Dd, Tq, Tq, NT, Dd,
                 (long long)Tq * Tq, (long long)Tq, (long long)Tq * Dd, Bq, 2 /*scale-then-bias*/);
}

// Round 5
// 707.312 us; speedup vs baseline: 1.1533x; 1.1533x over previous
//
#include <hip/hip_runtime.h>
#include <stdint.h>

// ---------------------------------------------------------------------------
// AstroSymbolicEpisodicLayer  (B=4, TQ=TK=2048, D=1024, R=64, H=512)
// R8: grid-utilization round.
//  * gemm256m: descriptor-based multi-op 256^2 GEMM (R6 inner loop unchanged).
//    One launch runs {Wq-proj, KF, Wov, MLP1} = 448 blocks (was 3x128+64
//    half-machine dispatches). Buffer re-aliasing: KF->B5, kbraw->B1.
//  * context + ITab GEMMs -> gemm_bt (512-block grids, multi-block/CU) instead
//    of 128-block gemm256 (half machine idle).
//  * scores stays on 256-block gemm256m (fills chip exactly).
// R7 sched_barrier pins reverted (measured null). Carries R4 folding, R5/R6
// 256^2 swizzled-LDS schedule + XCD swizzle.
// ---------------------------------------------------------------------------

#define Bq 4
#define Tq 2048
#define Dd 1024
#define NT 8192      // B*T
#define Hh 512
#define Rr_ 64
#define FQ 1024      // packed rfft spectrum width: re(0..512) | im(1..511)

typedef unsigned short ushort_t;
typedef short s16x8 __attribute__((ext_vector_type(8)));
typedef float floatx4 __attribute__((ext_vector_type(4)));

__device__ __forceinline__ float b2f(ushort_t s) {
  unsigned u = (unsigned)s << 16;
  return __builtin_bit_cast(float, u);
}
__device__ __forceinline__ ushort_t f2b(float f) {
  unsigned u = __builtin_bit_cast(unsigned, f);
  unsigned r = (u + 0x7fffu + ((u >> 16) & 1u)) >> 16;
  return (ushort_t)r;
}

__device__ __forceinline__ void load_lds16(const void* g, void* l) {
  __builtin_amdgcn_global_load_lds((__attribute__((address_space(1))) void*)(g),
                                   (__attribute__((address_space(3))) void*)(l),
                                   16, 0, 0);
}

// bijective XCD-aware remap (m204 form) over a 3-D grid (for gemm_bt).
__device__ __forceinline__ void xcd_swizzle(int& bx, int& by, int& bz) {
  const int gx = gridDim.x, gy = gridDim.y, gz = gridDim.z;
  const int nwg = gx * gy * gz;
  const int orig = (bz * gy + by) * gx + bx;
  const int q = nwg >> 3, r = nwg & 7;
  const int x = orig & 7, i = orig >> 3;
  const int wg = (x < r ? x * (q + 1) : r * (q + 1) + (x - r) * q) + i;
  bx = wg % gx;
  const int t = wg / gx;
  by = t % gy;
  bz = t / gy;
}

// ---------------------------------------------------------------------------
// gemm256m: descriptor-based multi-op 256x256 GEMM.
// Per op: C[M,N] = A[M,K] @ Bt[N,K]^T, tile 256x256, BK=64, 8 waves (2Mx4N),
// wave tile 128x64. LDS 128 KiB: [slot][A/B][khalf][256][32], chunk-rotation
// swizzle (conflict-free ds_read_b128, measured 0 conflicts). R6 schedule:
// one counted vmcnt(4) per K-tile, double barrier per phase, setprio on MFMA.
// Up to 4 ops per launch; flat blockIdx.x -> bijective XCD swizzle -> op scan
// -> (bx,by,bz). All ops must have K % 128 == 0.
// ---------------------------------------------------------------------------
struct GOp {
  const ushort_t* A; const ushort_t* Bt;
  float* C; ushort_t* Cbf;
  const float* bias_col; const float* bias_row;
  const float* rmul; const float* cmul; const float* tau;
  float* rowsum;
  int rmulStride, cmulStride, rsStride, rsMode;
  int K, lda, ldb, ldc, flags;
  long long sA, sB, sC;
  int gx, gy, blkStart, pad;
};
struct GB { GOp op[4]; int nOps; int totBlk; };

__global__ __launch_bounds__(512, 2) void gemm256m(GB gb) {
  __shared__ __align__(16) ushort_t lds[2][2][2][256][32];

  // bijective XCD swizzle over the flat merged grid
  int bid = blockIdx.x;
  {
    const int nwg = gb.totBlk;
    const int q = nwg >> 3, r = nwg & 7;
    const int x = bid & 7, i = bid >> 3;
    bid = (x < r ? x * (q + 1) : r * (q + 1) + (x - r) * q) + i;
  }
  // find op (ops sorted by blkStart)
  int oi = 0;
#pragma unroll
  for (int k = 1; k < 4; k++)
    if (k < gb.nOps && bid >= gb.op[k].blkStart) oi = k;
  const GOp o = gb.op[oi];
  const int local = bid - o.blkStart;
  const int bx = local % o.gx;
  const int tt_ = local / o.gx;
  const int by = tt_ % o.gy;
  const int bz = tt_ / o.gy;

  const ushort_t* Ab = o.A + (size_t)bz * o.sA;
  const ushort_t* Bb = o.Bt + (size_t)bz * o.sB;
  const int tm   = by * 256;
  const int tn   = bx * 256;
  const int tid  = threadIdx.x;
  const int wave = tid >> 6;        // 0..7
  const int lane = tid & 63;
  const int wm   = wave >> 2;       // 0..1 -> A rows wm*128..+127
  const int wn   = wave & 3;        // 0..3 -> B rows wn*64..+63

  const int s_r  = lane >> 2;                       // 0..15
  const int s_cg = (((lane & 3) - (s_r >> 1)) & 3); // inverse-permuted chunk
  const int f_r  = lane & 15;
  const int f_p  = ((((lane >> 4) + (f_r >> 1)) & 3) << 3);

  const int lda = o.lda, ldb = o.ldb;
  const int NTILES = o.K >> 6;

  floatx4 acc[8][4] = {};

  // stage group g (0=A.k0, 1=B.k0, 2=A.k1, 3=B.k1) of tile tt into slot sl
#define STAGE256(tt, g, sl)                                                     \
  do {                                                                          \
    const int mat_ = (g) & 1, h_ = (g) >> 1;                                    \
    const ushort_t* src_ = mat_ ? Bb : Ab;                                      \
    const int ld_ = mat_ ? ldb : lda;                                           \
    const int tb_ = mat_ ? tn : tm;                                             \
    const int kofs_ = (tt) * 64 + h_ * 32 + s_cg * 8;                           \
    _Pragma("unroll")                                                           \
    for (int j_ = 0; j_ < 2; j_++) {                                            \
      const int slab_ = wave * 2 + j_;                                          \
      const ushort_t* gp_ = src_ + (size_t)(tb_ + slab_ * 16 + s_r) * ld_ + kofs_; \
      load_lds16(gp_, (void*)&lds[sl][mat_][h_][slab_ * 16][0]);                \
    }                                                                           \
  } while (0)

  // prologue: tile0 fully + tile1 k0 groups; vmcnt(4) -> tile0 landed
  STAGE256(0, 0, 0);
  STAGE256(0, 1, 0);
  STAGE256(0, 2, 0);
  STAGE256(0, 3, 0);
  STAGE256(1, 0, 1);
  STAGE256(1, 1, 1);
  asm volatile("s_waitcnt vmcnt(4)" ::: "memory");
  __builtin_amdgcn_s_barrier();

  for (int t = 0; t < NTILES; t++) {
    const int sl  = t & 1;
    const int sl1 = sl ^ 1;
    const int t1  = (t + 1 < NTILES) ? t + 1 : t;  // clamped tail (writes go to
    const int t2  = (t + 2 < NTILES) ? t + 2 : t;  // never-again-read regions)
    s16x8 a[8], b[4];

    // ---- ph0: read k0 frags, stage A.k1(t+1), MFMA k0 x n{0,1} ----
#pragma unroll
    for (int m = 0; m < 8; m++)
      a[m] = *(const s16x8*)&lds[sl][0][0][wm * 128 + m * 16 + f_r][f_p];
#pragma unroll
    for (int n = 0; n < 4; n++)
      b[n] = *(const s16x8*)&lds[sl][1][0][wn * 64 + n * 16 + f_r][f_p];
    STAGE256(t1, 2, sl1);
    __builtin_amdgcn_s_barrier();
    __builtin_amdgcn_s_setprio(1);
#pragma unroll
    for (int m = 0; m < 8; m++)
#pragma unroll
      for (int n = 0; n < 2; n++)
        acc[m][n] = __builtin_amdgcn_mfma_f32_16x16x32_bf16(a[m], b[n], acc[m][n], 0, 0, 0);
    __builtin_amdgcn_s_setprio(0);
    __builtin_amdgcn_s_barrier();

    // ---- ph1: stage B.k1(t+1), MFMA k0 x n{2,3} ----
    STAGE256(t1, 3, sl1);
    __builtin_amdgcn_s_barrier();
    __builtin_amdgcn_s_setprio(1);
#pragma unroll
    for (int m = 0; m < 8; m++)
#pragma unroll
      for (int n = 2; n < 4; n++)
        acc[m][n] = __builtin_amdgcn_mfma_f32_16x16x32_bf16(a[m], b[n], acc[m][n], 0, 0, 0);
    __builtin_amdgcn_s_setprio(0);
    __builtin_amdgcn_s_barrier();

    // ---- ph2: read k1 frags, stage A.k0(t+2) into consumed region ----
#pragma unroll
    for (int m = 0; m < 8; m++)
      a[m] = *(const s16x8*)&lds[sl][0][1][wm * 128 + m * 16 + f_r][f_p];
#pragma unroll
    for (int n = 0; n < 4; n++)
      b[n] = *(const s16x8*)&lds[sl][1][1][wn * 64 + n * 16 + f_r][f_p];
    STAGE256(t2, 0, sl);
    __builtin_amdgcn_s_barrier();
    __builtin_amdgcn_s_setprio(1);
#pragma unroll
    for (int m = 0; m < 8; m++)
#pragma unroll
      for (int n = 0; n < 2; n++)
        acc[m][n] = __builtin_amdgcn_mfma_f32_16x16x32_bf16(a[m], b[n], acc[m][n], 0, 0, 0);
    __builtin_amdgcn_s_setprio(0);
    __builtin_amdgcn_s_barrier();

    // ---- ph3: stage B.k0(t+2), MFMA k1 x n{2,3}, vmcnt(4) ----
    STAGE256(t2, 1, sl);
    __builtin_amdgcn_s_barrier();
    __builtin_amdgcn_s_setprio(1);
#pragma unroll
    for (int m = 0; m < 8; m++)
#pragma unroll
      for (int n = 2; n < 4; n++)
        acc[m][n] = __builtin_amdgcn_mfma_f32_16x16x32_bf16(a[m], b[n], acc[m][n], 0, 0, 0);
    __builtin_amdgcn_s_setprio(0);
    asm volatile("s_waitcnt vmcnt(4)" ::: "memory");  // tile t+1 fully landed
    __builtin_amdgcn_s_barrier();
  }
#undef STAGE256

  // ---- epilogue ----
  const float tv = o.tau ? o.tau[bz] : 0.f;
  float*   Cp  = o.C   ? o.C   + (size_t)bz * o.sC : nullptr;
  ushort_t* Cb = o.Cbf ? o.Cbf + (size_t)bz * o.sC : nullptr;
  float bcv[4], cmv[4];
#pragma unroll
  for (int n = 0; n < 4; n++) {
    const int col = tn + wn * 64 + n * 16 + (lane & 15);
    bcv[n] = o.bias_col ? o.bias_col[col] : 0.f;
    cmv[n] = o.cmul ? o.cmul[(size_t)bz * o.cmulStride + col] : 1.f;
  }
#pragma unroll
  for (int m = 0; m < 8; m++) {
#pragma unroll
    for (int r = 0; r < 4; r++) {
      const int row = tm + wm * 128 + m * 16 + (lane >> 4) * 4 + r;
      const float rm = o.rmul ? o.rmul[(size_t)bz * o.rmulStride + row] : 1.f;
      const float br = o.bias_row ? o.bias_row[row] : 0.f;
      float rsum = 0.f;
#pragma unroll
      for (int n = 0; n < 4; n++) {
        const int col = tn + wn * 64 + n * 16 + (lane & 15);
        float v;
        if (o.flags & 2) {
          v = acc[m][n][r] * (rm * cmv[n]) + bcv[n] + br;   // scale-then-bias
        } else {
          v = (acc[m][n][r] + bcv[n] + br) * (rm * cmv[n]);
        }
        if (o.flags & 1) v = fmaxf(v, 0.f);
        if (o.tau) { float d = 1.0f - v; v = fmaxf(1.0f - tv * 0.25f * d * d, 0.f); }
        rsum += (o.rsMode == 2) ? v * v : v;
        if (Cp) Cp[(size_t)row * o.ldc + col] = v;
        if (Cb) Cb[(size_t)row * o.ldc + col] = f2b(v);
      }
      if (o.rsMode == 1 || o.rsMode == 2) {
        rsum += __shfl_xor(rsum, 1);
        rsum += __shfl_xor(rsum, 2);
        rsum += __shfl_xor(rsum, 4);
        rsum += __shfl_xor(rsum, 8);
        if ((lane & 15) == 0)
          atomicAdd(&o.rowsum[(size_t)bz * o.rsStride + row], rsum);
      }
    }
  }
}

// ---------------------------------------------------------------------------
// gemm_bt: 128x128 kernel (multi-block/CU; used where grids would leave the
// 256^2 kernel at half machine: context, ITab, MLP2, RF) + XCD swizzle
// ---------------------------------------------------------------------------
__global__ __launch_bounds__(256) void gemm_bt(
    const ushort_t* __restrict__ A, const ushort_t* __restrict__ Bt,
    float* __restrict__ C, ushort_t* __restrict__ Cbf,
    const float* __restrict__ bias_col, const float* __restrict__ bias_row,
    const float* __restrict__ rmul, int rmulStride,
    const float* __restrict__ cmul, int cmulStride,
    const float* __restrict__ tau,
    float* __restrict__ rowsum, int rsStride, int rsMode,
    int K, int lda, int ldb, int ldc,
    long long sA, long long sB, long long sC, int flags)
{
  __shared__ __align__(16) ushort_t As[128 * 32];
  __shared__ __align__(16) ushort_t Bs[128 * 32];

  int bx = blockIdx.x, by = blockIdx.y, bz = blockIdx.z;
  xcd_swizzle(bx, by, bz);
  const ushort_t* Ab = A + (size_t)bz * sA;
  const ushort_t* Bb = Bt + (size_t)bz * sB;
  const int tm   = by * 128;
  const int tn   = bx * 128;
  const int tid  = threadIdx.x;
  const int wave = tid >> 6;
  const int lane = tid & 63;
  const int wm   = (wave & 1) << 6;
  const int wn   = (wave >> 1) << 6;
  const int sr   = lane >> 2;
  const int cp   = lane & 3;
  const int sc   = (((cp - (sr >> 1)) & 3) << 3);
  const int fr   = lane & 15;
  const int fk   = ((((lane >> 4) + (fr >> 1)) & 3) << 3);

  floatx4 acc[4][4] = {};

  for (int k0 = 0; k0 < K; k0 += 32) {
    {
      const ushort_t* gA0 = Ab + (size_t)(tm + wave * 16 + sr) * lda + (k0 + sc);
      const ushort_t* gA1 = gA0 + (size_t)64 * lda;
      char* lA = (char*)As + wave * 1024;
      load_lds16(gA0, lA);
      load_lds16(gA1, lA + 4096);
      const ushort_t* gB0 = Bb + (size_t)(tn + wave * 16 + sr) * ldb + (k0 + sc);
      const ushort_t* gB1 = gB0 + (size_t)64 * ldb;
      char* lB = (char*)Bs + wave * 1024;
      load_lds16(gB0, lB);
      load_lds16(gB1, lB + 4096);
    }
    __syncthreads();
    s16x8 af[4], bfv[4];
#pragma unroll
    for (int i = 0; i < 4; i++)
      af[i] = *(const s16x8*)&As[(wm + i * 16 + fr) * 32 + fk];
#pragma unroll
    for (int j = 0; j < 4; j++)
      bfv[j] = *(const s16x8*)&Bs[(wn + j * 16 + fr) * 32 + fk];
#pragma unroll
    for (int i = 0; i < 4; i++)
#pragma unroll
      for (int j = 0; j < 4; j++)
        acc[i][j] = __builtin_amdgcn_mfma_f32_16x16x32_bf16(af[i], bfv[j], acc[i][j], 0, 0, 0);
    __syncthreads();
  }

  const float tv = tau ? tau[bz] : 0.f;
  float*   Cp  = C   ? C   + (size_t)bz * sC : nullptr;
  ushort_t* Cb = Cbf ? Cbf + (size_t)bz * sC : nullptr;
  float bcv[4], cmv[4];
#pragma unroll
  for (int j = 0; j < 4; j++) {
    const int col = tn + wn + j * 16 + (lane & 15);
    bcv[j] = bias_col ? bias_col[col] : 0.f;
    cmv[j] = cmul ? cmul[(size_t)bz * cmulStride + col] : 1.f;
  }
#pragma unroll
  for (int i = 0; i < 4; i++) {
#pragma unroll
    for (int r = 0; r < 4; r++) {
      const int row = tm + wm + i * 16 + (lane >> 4) * 4 + r;
      const float rm = rmul ? rmul[(size_t)bz * rmulStride + row] : 1.f;
      const float br = bias_row ? bias_row[row] : 0.f;
      float rsum = 0.f;
#pragma unroll
      for (int j = 0; j < 4; j++) {
        const int col = tn + wn + j * 16 + (lane & 15);
        float v;
        if (flags & 2) {
          v = acc[i][j][r] * (rm * cmv[j]) + bcv[j] + br;
        } else {
          v = (acc[i][j][r] + bcv[j] + br) * (rm * cmv[j]);
        }
        if (flags & 1) v = fmaxf(v, 0.f);
        if (tau) { float d = 1.0f - v; v = fmaxf(1.0f - tv * 0.25f * d * d, 0.f); }
        rsum += (rsMode == 2) ? v * v : v;
        if (Cp) Cp[(size_t)row * ldc + col] = v;
        if (Cb) Cb[(size_t)row * ldc + col] = f2b(v);
      }
      if (rsMode == 1 || rsMode == 2) {
        rsum += __shfl_xor(rsum, 1);
        rsum += __shfl_xor(rsum, 2);
        rsum += __shfl_xor(rsum, 4);
        rsum += __shfl_xor(rsum, 8);
        if ((lane & 15) == 0)
          atomicAdd(&rowsum[(size_t)bz * rsStride + row], rsum);
      }
    }
  }
}

// ---------------------------------------------------------------------------
// prep3: batched weight-product GEMMs (K=1024, bf16 out)
// ---------------------------------------------------------------------------
struct P3 { const ushort_t* A[3]; const ushort_t* Bt[3]; ushort_t* C[3]; int M[3]; };

__global__ __launch_bounds__(256) void prep3(P3 p) {
  __shared__ __align__(16) ushort_t As[128 * 32];
  __shared__ __align__(16) ushort_t Bs[128 * 32];
  const int z  = blockIdx.z;
  const int tm = blockIdx.y * 128;
  if (tm >= p.M[z]) return;
  const ushort_t* Ab = p.A[z];
  const ushort_t* Bb = p.Bt[z];
  ushort_t*       Cc = p.C[z];
  const int tn   = blockIdx.x * 128;
  const int tid  = threadIdx.x;
  const int wave = tid >> 6;
  const int lane = tid & 63;
  const int wm   = (wave & 1) << 6;
  const int wn   = (wave >> 1) << 6;
  const int sr   = lane >> 2;
  const int cp   = lane & 3;
  const int sc   = (((cp - (sr >> 1)) & 3) << 3);
  const int fr   = lane & 15;
  const int fk   = ((((lane >> 4) + (fr >> 1)) & 3) << 3);

  floatx4 acc[4][4] = {};

  for (int k0 = 0; k0 < Dd; k0 += 32) {
    {
      const ushort_t* gA0 = Ab + (size_t)(tm + wave * 16 + sr) * Dd + (k0 + sc);
      const ushort_t* gA1 = gA0 + (size_t)64 * Dd;
      char* lA = (char*)As + wave * 1024;
      load_lds16(gA0, lA);
      load_lds16(gA1, lA + 4096);
      const ushort_t* gB0 = Bb + (size_t)(tn + wave * 16 + sr) * Dd + (k0 + sc);
      const ushort_t* gB1 = gB0 + (size_t)64 * Dd;
      char* lB = (char*)Bs + wave * 1024;
      load_lds16(gB0, lB);
      load_lds16(gB1, lB + 4096);
    }
    __syncthreads();
    s16x8 af[4], bfv[4];
#pragma unroll
    for (int i = 0; i < 4; i++)
      af[i] = *(const s16x8*)&As[(wm + i * 16 + fr) * 32 + fk];
#pragma unroll
    for (int j = 0; j < 4; j++)
      bfv[j] = *(const s16x8*)&Bs[(wn + j * 16 + fr) * 32 + fk];
#pragma unroll
    for (int i = 0; i < 4; i++)
#pragma unroll
      for (int j = 0; j < 4; j++)
        acc[i][j] = __builtin_amdgcn_mfma_f32_16x16x32_bf16(af[i], bfv[j], acc[i][j], 0, 0, 0);
    __syncthreads();
  }

#pragma unroll
  for (int i = 0; i < 4; i++)
#pragma unroll
    for (int r = 0; r < 4; r++) {
      const int row = tm + wm + i * 16 + (lane >> 4) * 4 + r;
#pragma unroll
      for (int j = 0; j < 4; j++) {
        const int col = tn + wn + j * 16 + (lane & 15);
        Cc[(size_t)row * Dd + col] = f2b(acc[i][j][r]);
      }
    }
}

// ---------------------------------------------------------------------------
// small kernels
// ---------------------------------------------------------------------------
__global__ __launch_bounds__(256) void castbf(const float* __restrict__ in,
                                              ushort_t* __restrict__ out, int n4) {
  int i = blockIdx.x * 256 + threadIdx.x;
  if (i >= n4) return;
  float4 v = ((const float4*)in)[i];
  ushort4 o;
  o.x = f2b(v.x); o.y = f2b(v.y); o.z = f2b(v.z); o.w = f2b(v.w);
  ((ushort4*)out)[i] = o;
}

struct TC4 { const float* in[4]; ushort_t* out[4]; };
__global__ __launch_bounds__(256) void tcast4(TC4 p) {
  __shared__ float t[32][33];
  int z = blockIdx.z;
  const float* in = p.in[z];
  ushort_t* out = p.out[z];
  int r0 = blockIdx.x * 32, c0 = blockIdx.y * 32;
  int x = threadIdx.x, y = threadIdx.y;
  for (int dy = 0; dy < 32; dy += 8)
    t[y + dy][x] = in[(size_t)(r0 + y + dy) * 1024 + c0 + x];
  __syncthreads();
  for (int dy = 0; dy < 32; dy += 8)
    out[(size_t)(c0 + y + dy) * 1024 + r0 + x] = f2b(t[x][y + dy]);
}

__global__ __launch_bounds__(256) void tcast(const float* __restrict__ in,
                                             ushort_t* __restrict__ out,
                                             int RrN, int Cc, int Cp) {
  __shared__ float t[32][33];
  int r0 = blockIdx.x * 32, c0 = blockIdx.y * 32;
  int x = threadIdx.x, y = threadIdx.y;
  for (int dy = 0; dy < 32; dy += 8) {
    int r = r0 + y + dy, c = c0 + x;
    t[y + dy][x] = (c < Cc) ? in[(size_t)r * Cc + c] : 0.f;
  }
  __syncthreads();
  for (int dy = 0; dy < 32; dy += 8) {
    int c = c0 + y + dy, r = r0 + x;
    if (c < Cp) out[(size_t)c * RrN + r] = f2b(t[x][y + dy]);
  }
}

__global__ __launch_bounds__(256) void rolenorm(const float* __restrict__ rm,
                                                ushort_t* __restrict__ rmn) {
  int r = blockIdx.x, tid = threadIdx.x;
  float4 v = ((const float4*)(rm + (size_t)r * 1024))[tid];
  float s = v.x * v.x + v.y * v.y + v.z * v.z + v.w * v.w;
#pragma unroll
  for (int m = 1; m < 64; m <<= 1) s += __shfl_xor(s, m);
  __shared__ float red[6];
  if ((tid & 63) == 0) red[tid >> 6] = s;
  __syncthreads();
  if (tid == 0) red[4] = 1.f / fmaxf(sqrtf(red[0] + red[1] + red[2] + red[3]), 1e-12f);
  __syncthreads();
  float inv = red[4];
  ushort4 o;
  o.x = f2b(v.x * inv); o.y = f2b(v.y * inv); o.z = f2b(v.z * inv); o.w = f2b(v.w * inv);
  ((ushort4*)(rmn + (size_t)r * 1024))[tid] = o;
}

__global__ __launch_bounds__(256) void rfn_kernel(const ushort_t* __restrict__ rmn,
                                                  const ushort_t* __restrict__ ftab,
                                                  ushort_t* __restrict__ RFnT) {
  int f = blockIdx.x;
  int t = threadIdx.x;
  int r = t >> 2, part = t & 3;
  const ushort_t* fr = ftab + (size_t)f * 1024 + part * 256;
  const ushort_t* rr = rmn + (size_t)r * 1024 + part * 256;
  float s = 0.f;
#pragma unroll 4
  for (int i = 0; i < 32; i++) {
    s16x8 a = *(const s16x8*)(fr + i * 8);
    s16x8 b = *(const s16x8*)(rr + i * 8);
#pragma unroll
    for (int j = 0; j < 8; j++) s += b2f((ushort_t)a[j]) * b2f((ushort_t)b[j]);
  }
  s += __shfl_xor(s, 1);
  s += __shfl_xor(s, 2);
  if (part == 0) RFnT[(size_t)f * 128 + r] = f2b(s);
}

__global__ __launch_bounds__(64) void foldbk(const ushort_t* __restrict__ ftab,
                                             const float* __restrict__ bk,
                                             float* __restrict__ bkF) {
  int j = blockIdx.x, lane = threadIdx.x;
  const ushort_t* row = ftab + (size_t)j * 1024 + lane * 16;
  const float* bp = bk + lane * 16;
  float s = 0.f;
#pragma unroll
  for (int i = 0; i < 2; i++) {
    s16x8 a = *(const s16x8*)(row + i * 8);
#pragma unroll
    for (int e = 0; e < 8; e++) s += b2f((ushort_t)a[e]) * bp[i * 8 + e];
  }
#pragma unroll
  for (int m = 1; m < 64; m <<= 1) s += __shfl_xor(s, m);
  if (lane == 0) bkF[j] = s;
}

__global__ __launch_bounds__(256) void foldbh(const float* __restrict__ Wr1,
                                              const float* __restrict__ bk,
                                              const float* __restrict__ br1,
                                              float* __restrict__ bh) {
  int h = blockIdx.x * 256 + threadIdx.x;
  float s = br1[h];
  for (int d = 0; d < 1024; d++) s += bk[d] * Wr1[(size_t)d * Hh + h];
  bh[h] = s;
}

__global__ __launch_bounds__(256) void foldbvo(const float* __restrict__ Wo,
                                               const float* __restrict__ bv,
                                               const float* __restrict__ bo,
                                               float* __restrict__ bvo) {
  int d = blockIdx.x * 256 + threadIdx.x;
  float s = bo[d];
  for (int e = 0; e < 1024; e++) s += bv[e] * Wo[(size_t)e * 1024 + d];
  bvo[d] = s;
}

__global__ __launch_bounds__(256) void invnorm_surprise(const float* __restrict__ ssq,
                                                        float* __restrict__ invn,
                                                        float* __restrict__ ssum) {
  int row = blockIdx.x * 256 + threadIdx.x;
  float nrm = sqrtf(ssq[row]);
  invn[row] = 1.f / fmaxf(nrm, 1e-12f);
  float t = nrm;
#pragma unroll
  for (int m = 1; m < 64; m <<= 1) t += __shfl_xor(t, m);
  if ((threadIdx.x & 63) == 0) atomicAdd(&ssum[row >> 11], t);
}

__global__ __launch_bounds__(256) void invnorm(const float* __restrict__ ssq,
                                               float* __restrict__ invn) {
  int row = blockIdx.x * 256 + threadIdx.x;
  invn[row] = 1.f / fmaxf(sqrtf(ssq[row]), 1e-12f);
}

__global__ __launch_bounds__(256) void invrowsum(const float* __restrict__ rs,
                                                 float* __restrict__ inv) {
  int row = blockIdx.x * 256 + threadIdx.x;
  inv[row] = 1.f / fmaxf(rs[row], 1e-9f);
}

__global__ void finalize_astro(const float* __restrict__ ssum, const float* __restrict__ astro,
                               const float* __restrict__ ascale, float* __restrict__ tau,
                               float* __restrict__ outTail) {
  int b = threadIdx.x;
  if (b < Bq) {
    float mean = ssum[b] * (1.f / (32.f * 2048.f));
    float ns = 0.95f * astro[b] + 0.05f * mean;
    tau[b] = fmaxf(1.f + ascale[0] * ns, 0.001f);
    outTail[b] = ns;
  }
}

__global__ __launch_bounds__(256) void softmax64(const float* __restrict__ logits,
                                                 ushort_t* __restrict__ out) {
  int row = blockIdx.x * 4 + (threadIdx.x >> 6);
  int lane = threadIdx.x & 63;
  float x = logits[(size_t)row * 128 + lane];
  float m = x;
#pragma unroll
  for (int s = 1; s < 64; s <<= 1) m = fmaxf(m, __shfl_xor(m, s));
  float e = expf(x - m);
  float sum = e;
#pragma unroll
  for (int s = 1; s < 64; s <<= 1) sum += __shfl_xor(sum, s);
  out[(size_t)row * 64 + lane] = f2b(e / sum);
}

__global__ __launch_bounds__(256) void gen_ftab(ushort_t* __restrict__ ftab) {
  const float TW = 6.283185307179586f / 1024.f;
  int idx = blockIdx.x * 256 + threadIdx.x;
  int j = idx >> 10, k = idx & 1023;
  int f = j <= 512 ? j : j - 512;
  float th = (float)((f * k) & 1023) * TW;
  float sv, cv; sincosf(th, &sv, &cv);
  ftab[idx] = f2b(j <= 512 ? cv : -sv);
}

__global__ __launch_bounds__(256) void gen_itab(ushort_t* __restrict__ itab) {
  const float TW = 6.283185307179586f / 1024.f;
  int idx = blockIdx.x * 256 + threadIdx.x;
  int n = idx >> 10, j = idx & 1023;
  float v;
  if (j <= 512) {
    float w = (j == 0 || j == 512) ? (1.f / 1024.f) : (2.f / 1024.f);
    float th = (float)((j * n) & 1023) * TW;
    float sv, cv; sincosf(th, &sv, &cv);
    v = w * cv;
  } else {
    int f = j - 512;
    float th = (float)((f * n) & 1023) * TW;
    float sv, cv; sincosf(th, &sv, &cv);
    v = -(2.f / 1024.f) * sv;
  }
  itab[idx] = f2b(v);
}

__global__ __launch_bounds__(256) void fftmul(const ushort_t* __restrict__ KF,
                                              const ushort_t* __restrict__ RF,
                                              ushort_t* __restrict__ P) {
  int idx = blockIdx.x * 256 + threadIdx.x;
  int t = idx >> 9;
  int j = idx & 511;
  size_t base = (size_t)t * FQ;
  if (j == 0) {
    P[base]       = f2b(b2f(KF[base]) * b2f(RF[base]));
    P[base + 512] = f2b(b2f(KF[base + 512]) * b2f(RF[base + 512]));
  } else {
    float a = b2f(KF[base + j]), b = b2f(KF[base + 512 + j]);
    float c = b2f(RF[base + j]), d = b2f(RF[base + 512 + j]);
    P[base + j]       = f2b(a * c - b * d);
    P[base + 512 + j] = f2b(a * d + b * c);
  }
}

// ---------------------------------------------------------------------------
// workspace layout (bytes, 256-aligned)
// Lifetimes (R8): B1 = qbf (dead after mergeA) -> kbraw; B2 = kinb -> RF;
// B3 = vinb -> Pb; B4 = qraw; B5 = KF (dead after fftmul, reused? no - stays);
// B6 = folded weights; B7 = vT.
// ---------------------------------------------------------------------------
static constexpr size_t OFF_RS    = 0;
static constexpr size_t OFF_SSQQ  = 32768;
static constexpr size_t OFF_SSQK  = 65536;
static constexpr size_t OFF_INVQ  = 98304;
static constexpr size_t OFF_INVK  = 131072;
static constexpr size_t OFF_INVRS = 163840;
static constexpr size_t OFF_SSUM  = 196608;
static constexpr size_t OFF_TAU   = 196864;
static constexpr size_t OFF_WQT   = 197120;
static constexpr size_t OFF_WKB   = OFF_WQT  + 2097152;
static constexpr size_t OFF_WVB   = OFF_WKB  + 2097152;
static constexpr size_t OFF_WOT   = OFF_WVB  + 2097152;
static constexpr size_t OFF_WR1T  = OFF_WOT  + 2097152;
static constexpr size_t OFF_WR2T  = OFF_WR1T + 1048576;
static constexpr size_t OFF_RMN   = OFF_WR2T + 131072;
static constexpr size_t OFF_FTAB  = OFF_RMN  + 131072;
static constexpr size_t OFF_ITAB  = OFF_FTAB + 2097152;
static constexpr size_t OFF_RFNT  = OFF_ITAB + 2097152;
static constexpr size_t OFF_B1    = OFF_RFNT + 262144;
static constexpr size_t OFF_B2    = OFF_B1   + 16777216;
static constexpr size_t OFF_B3    = OFF_B2   + 16777216;
static constexpr size_t OFF_B4    = OFF_B3   + 16777216;
static constexpr size_t OFF_B5    = OFF_B4   + 16777216;
static constexpr size_t OFF_B6    = OFF_B5   + 16777216;
static constexpr size_t OFF_B7    = OFF_B6   + 16777216;
static constexpr size_t OFF_HID   = OFF_B7   + 16777216;
static constexpr size_t OFF_LOGI  = OFF_HID  + 8388608;
static constexpr size_t OFF_RW    = OFF_LOGI + 4194304;
static constexpr size_t OFF_SB    = OFF_RW   + 1048576;
static constexpr size_t WS_NEEDED = OFF_SB   + 33554432;
static constexpr size_t OFF_WKF   = OFF_B6;
static constexpr size_t OFF_WOV   = OFF_B6 + 2097152;
static constexpr size_t OFF_WKR1  = OFF_B6 + 4194304;
static constexpr size_t OFF_BKF   = OFF_B6 + 5242880;
static constexpr size_t OFF_BH    = OFF_B6 + 5247232;
static constexpr size_t OFF_BVO   = OFF_B6 + 5249536;

static inline void launch_gemm(hipStream_t s, const ushort_t* A, const ushort_t* Bt,
                               float* Cf, ushort_t* Cb,
                               const float* bias_col, const float* bias_row,
                               const float* rmul, int rmulStride,
                               const float* cmul, int cmulStride,
                               const float* tau, float* rowsum, int rsStride, int rsMode,
                               int M, int N, int K, int lda, int ldb, int ldc,
                               long long sA, long long sB, long long sC, int Z, int flags) {
  dim3 g(N / 128, M / 128, Z), b(256);
  gemm_bt<<<g, b, 0, s>>>(A, Bt, Cf, Cb, bias_col, bias_row, rmul, rmulStride,
                          cmul, cmulStride, tau, rowsum, rsStride, rsMode,
                          K, lda, ldb, ldc, sA, sB, sC, flags);
}

static inline GOp mkop(const ushort_t* A, const ushort_t* Bt, float* Cf, ushort_t* Cb,
                       const float* bias_col, const float* rmul, int rmulStride,
                       const float* cmul, int cmulStride, const float* tau,
                       float* rowsum, int rsStride, int rsMode,
                       int M, int N, int K, int lda, int ldb, int ldc,
                       long long sA, long long sB, long long sC, int flags, int blkStart) {
  GOp o;
  o.A = A; o.Bt = Bt; o.C = Cf; o.Cbf = Cb;
  o.bias_col = bias_col; o.bias_row = nullptr;
  o.rmul = rmul; o.cmul = cmul; o.tau = tau; o.rowsum = rowsum;
  o.rmulStride = rmulStride; o.cmulStride = cmulStride;
  o.rsStride = rsStride; o.rsMode = rsMode;
  o.K = K; o.lda = lda; o.ldb = ldb; o.ldc = ldc; o.flags = flags;
  o.sA = sA; o.sB = sB; o.sC = sC;
  o.gx = N / 256; o.gy = M / 256; o.blkStart = blkStart; o.pad = 0;
  return o;
}

extern "C" void kernel_launch(void* const* d_in, const int* in_sizes, int n_in,
                              void* d_out, int out_size, void* d_ws, size_t ws_size,
                              hipStream_t stream) {
  (void)in_sizes; (void)n_in; (void)out_size;
  if (ws_size < WS_NEEDED) return;

  const float* q_in  = (const float*)d_in[0];
  const float* k_in  = (const float*)d_in[1];
  const float* v_in  = (const float*)d_in[2];
  const float* astro = (const float*)d_in[3];
  const float* Wq    = (const float*)d_in[4];
  const float* bq    = (const float*)d_in[5];
  const float* Wk    = (const float*)d_in[6];
  const float* bk    = (const float*)d_in[7];
  const float* Wv    = (const float*)d_in[8];
  const float* bv    = (const float*)d_in[9];
  const float* Wo    = (const float*)d_in[10];
  const float* bo    = (const float*)d_in[11];
  const float* roleM = (const float*)d_in[12];
  const float* Wr1   = (const float*)d_in[13];
  const float* br1   = (const float*)d_in[14];
  const float* Wr2   = (const float*)d_in[15];
  const float* ascl  = (const float*)d_in[16];

  char* ws = (char*)d_ws;
  float*    rowsumS = (float*)(ws + OFF_RS);
  float*    ssqQ    = (float*)(ws + OFF_SSQQ);
  float*    ssqK    = (float*)(ws + OFF_SSQK);
  float*    invQ    = (float*)(ws + OFF_INVQ);
  float*    invK    = (float*)(ws + OFF_INVK);
  float*    invRS   = (float*)(ws + OFF_INVRS);
  float*    ssum    = (float*)(ws + OFF_SSUM);
  float*    tau     = (float*)(ws + OFF_TAU);
  ushort_t* WqT  = (ushort_t*)(ws + OFF_WQT);
  ushort_t* Wkb  = (ushort_t*)(ws + OFF_WKB);
  ushort_t* Wvb  = (ushort_t*)(ws + OFF_WVB);
  ushort_t* WoT  = (ushort_t*)(ws + OFF_WOT);
  ushort_t* Wr1T = (ushort_t*)(ws + OFF_WR1T);
  ushort_t* Wr2T = (ushort_t*)(ws + OFF_WR2T);
  ushort_t* rmn  = (ushort_t*)(ws + OFF_RMN);
  ushort_t* FTab = (ushort_t*)(ws + OFF_FTAB);
  ushort_t* ITab = (ushort_t*)(ws + OFF_ITAB);
  ushort_t* RFnT = (ushort_t*)(ws + OFF_RFNT);
  ushort_t* qbf  = (ushort_t*)(ws + OFF_B1);   // dead after mergeA
  ushort_t* kbraw= (ushort_t*)(ws + OFF_B1);   // written by ITab GEMM
  ushort_t* kinb = (ushort_t*)(ws + OFF_B2);
  ushort_t* RF   = (ushort_t*)(ws + OFF_B2);
  ushort_t* vinb = (ushort_t*)(ws + OFF_B3);
  ushort_t* Pb   = (ushort_t*)(ws + OFF_B3);
  ushort_t* qraw = (ushort_t*)(ws + OFF_B4);
  ushort_t* KF   = (ushort_t*)(ws + OFF_B5);   // moved off B1 (concurrent in mergeA)
  ushort_t* WkF  = (ushort_t*)(ws + OFF_WKF);
  ushort_t* Wov  = (ushort_t*)(ws + OFF_WOV);
  ushort_t* WkR1 = (ushort_t*)(ws + OFF_WKR1);
  float*    bkF  = (float*)(ws + OFF_BKF);
  float*    bh   = (float*)(ws + OFF_BH);
  float*    bvo  = (float*)(ws + OFF_BVO);
  ushort_t* vT   = (ushort_t*)(ws + OFF_B7);
  ushort_t* hid  = (ushort_t*)(ws + OFF_HID);
  float*    logi = (float*)(ws + OFF_LOGI);
  ushort_t* rw   = (ushort_t*)(ws + OFF_RW);
  ushort_t* Sb   = (ushort_t*)(ws + OFF_SB);
  float*    out  = (float*)d_out;

  // 0. zero accumulators
  hipMemsetAsync(ws, 0, OFF_SSUM + 256, stream);

  // 1. weight prep + tables
  TC4 tc4;
  tc4.in[0] = Wq; tc4.out[0] = WqT;
  tc4.in[1] = Wo; tc4.out[1] = WoT;
  tc4.in[2] = Wq; tc4.out[2] = WqT;
  tc4.in[3] = Wq; tc4.out[3] = WqT;
  tcast4<<<dim3(32, 32, 2), dim3(32, 8), 0, stream>>>(tc4);
  castbf<<<1024, 256, 0, stream>>>(Wk, Wkb, 262144);
  castbf<<<1024, 256, 0, stream>>>(Wv, Wvb, 262144);
  tcast<<<dim3(32, 16), dim3(32, 8), 0, stream>>>(Wr1, Wr1T, 1024, 512, 512);
  tcast<<<dim3(16, 4),  dim3(32, 8), 0, stream>>>(Wr2, Wr2T, 512, 64, 128);
  rolenorm<<<64, 256, 0, stream>>>(roleM, rmn);
  gen_ftab<<<(FQ * 1024) / 256, 256, 0, stream>>>(FTab);
  gen_itab<<<(1024 * FQ) / 256, 256, 0, stream>>>(ITab);
  rfn_kernel<<<FQ, 256, 0, stream>>>(rmn, FTab, RFnT);

  P3 p3;
  p3.A[0] = FTab; p3.Bt[0] = Wkb; p3.C[0] = WkF;  p3.M[0] = 1024;
  p3.A[1] = WoT;  p3.Bt[1] = Wvb; p3.C[1] = Wov;  p3.M[1] = 1024;
  p3.A[2] = Wr1T; p3.Bt[2] = Wkb; p3.C[2] = WkR1; p3.M[2] = 512;
  prep3<<<dim3(8, 8, 3), 256, 0, stream>>>(p3);
  foldbk<<<1024, 64, 0, stream>>>(FTab, bk, bkF);
  foldbh<<<Hh / 256, 256, 0, stream>>>(Wr1, bk, br1, bh);
  foldbvo<<<Dd / 256, 256, 0, stream>>>(Wo, bv, bo, bvo);

  // 2. input casts
  castbf<<<8192, 256, 0, stream>>>(q_in, qbf, NT * Dd / 4);
  castbf<<<8192, 256, 0, stream>>>(k_in, kinb, NT * Dd / 4);
  castbf<<<8192, 256, 0, stream>>>(v_in, vinb, NT * Dd / 4);

  // 3. mergeA: {Q-proj, KF, Vw^T, MLP1} in one 448-block launch
  {
    GB gb;
    // op0: qraw = qbf @ WqT^T + bq, ssqQ += v^2   (128 blocks)
    gb.op[0] = mkop(qbf, WqT, nullptr, qraw, bq, nullptr, 0, nullptr, 0, nullptr,
                    ssqQ, 0, 2, NT, Dd, Dd, Dd, Dd, Dd, 0, 0, 0, 0, 0);
    // op1: KF = kinb @ WkF^T + bkF               (128 blocks)
    gb.op[1] = mkop(kinb, WkF, nullptr, KF, bkF, nullptr, 0, nullptr, 0, nullptr,
                    nullptr, 0, 0, NT, FQ, Dd, Dd, Dd, FQ, 0, 0, 0, 0, 128);
    // op2: vT[d,t] = sum_c Wov[d,c] vinb[t,c]    (128 blocks)
    gb.op[2] = mkop(Wov, vinb, nullptr, vT, nullptr, nullptr, 0, nullptr, 0, nullptr,
                    nullptr, 0, 0, Dd, NT, Dd, Dd, Dd, NT, 0, 0, 0, 0, 256);
    // op3: hid = relu(kinb @ WkR1^T + bh)        (64 blocks)
    gb.op[3] = mkop(kinb, WkR1, nullptr, hid, bh, nullptr, 0, nullptr, 0, nullptr,
                    nullptr, 0, 0, NT, Hh, Dd, Dd, Dd, Hh, 0, 0, 0, 1 /*relu*/, 384);
    gb.nOps = 4; gb.totBlk = 448;
    gemm256m<<<dim3(448), dim3(512), 0, stream>>>(gb);
  }
  invnorm_surprise<<<NT / 256, 256, 0, stream>>>(ssqQ, invQ, ssum);
  finalize_astro<<<1, 64, 0, stream>>>(ssum, astro, ascl, tau, out + (size_t)NT * Dd);

  // 4. role path tail: MLP2 -> softmax -> RF
  launch_gemm(stream, hid, Wr2T, logi, nullptr, nullptr, nullptr,
              nullptr, 0, nullptr, 0, nullptr, nullptr, 0, 0,
              NT, 128, Hh, Hh, Hh, 128, 0, 0, 0, 1, 0);
  softmax64<<<NT / 4, 256, 0, stream>>>(logi, rw);
  launch_gemm(stream, rw, RFnT, nullptr, RF, nullptr, nullptr,
              nullptr, 0, nullptr, 0, nullptr, nullptr, 0, 0,
              NT, FQ, Rr_, Rr_, 128, FQ, 0, 0, 0, 1, 0);

  // 5. pointwise bind + inverse DFT (+sumsq) on gemm_bt (512 blocks)
  fftmul<<<(NT * 512) / 256, 256, 0, stream>>>(KF, RF, Pb);
  launch_gemm(stream, Pb, ITab, nullptr, kbraw, nullptr, nullptr,
              nullptr, 0, nullptr, 0, nullptr, ssqK, 0, 2,
              NT, Dd, FQ, FQ, FQ, Dd, 0, 0, 0, 1, 0);
  invnorm<<<NT / 256, 256, 0, stream>>>(ssqK, invK);

  // 6. attention scores on gemm256m (256 blocks fills chip)
  {
    GB gb;
    GOp o = mkop(qraw, kbraw, nullptr, Sb, nullptr, invQ, Tq, invK, Tq, tau,
                 rowsumS, Tq, 1, Tq, Tq, Dd, Dd, Dd, Tq,
                 (long long)Tq * Dd, (long long)Tq * Dd, (long long)Tq * Tq, 0, 0);
    gb.op[0] = o; gb.op[1] = o; gb.op[2] = o; gb.op[3] = o;
    gb.nOps = 1; gb.totBlk = 256;   // gx=8, gy=8, bz = 0..3 via local/(gx*gy)
    gemm256m<<<dim3(256), dim3(512), 0, stream>>>(gb);
  }
  invrowsum<<<NT / 256, 256, 0, stream>>>(rowsumS, invRS);

  // 7. context -> out on gemm_bt (512 blocks, 2 blocks/CU)
  launch_gemm(stream, Sb, vT, out, nullptr, bvo, nullptr,
              invRS, Tq, nullptr, 0, nullptr, nullptr, 0, 0,
              Tq, Dd, Tq, Tq, NT, Dd,
              (long long)Tq * Tq, (long long)Tq, (long long)Tq * Dd, Bq, 2 /*scale-then-bias*/);
}

// Round 6
// 696.408 us; speedup vs baseline: 1.1713x; 1.0157x over previous
//
#include <hip/hip_runtime.h>
#include <stdint.h>

// ---------------------------------------------------------------------------
// AstroSymbolicEpisodicLayer  (B=4, TQ=TK=2048, D=1024, R=64, H=512)
// R9: engine assignment by measured per-CU rate (all engines = ~1.65 TF/CU):
//  * mergeA {Qproj,KF,Wov,MLP1} on gemm_btm (multi-op 128^2, 1792 blocks,
//    3 blocks/CU -> full machine, no tails). 256^2 kernels reverted for these
//    (1 block/CU lost to no cross-block overlap; R5 measured 344 TF there).
//  * scores stays on gemm256m (256 blocks; measured best for this op).
//  * MLP2/RF/ITab/context on gemm_bt (512-block grids).
//  * castbf3: one launch casts q,k,v. titab: itab = pow2-scaled transpose of
//    ftab (bit-identical, replaces 4096-block sincos kernel).
// Carries R4 folds, R6 gemm256 schedule + XCD swizzle.
// ---------------------------------------------------------------------------

#define Bq 4
#define Tq 2048
#define Dd 1024
#define NT 8192      // B*T
#define Hh 512
#define Rr_ 64
#define FQ 1024      // packed rfft spectrum width: re(0..512) | im(1..511)

typedef unsigned short ushort_t;
typedef short s16x8 __attribute__((ext_vector_type(8)));
typedef float floatx4 __attribute__((ext_vector_type(4)));

__device__ __forceinline__ float b2f(ushort_t s) {
  unsigned u = (unsigned)s << 16;
  return __builtin_bit_cast(float, u);
}
__device__ __forceinline__ ushort_t f2b(float f) {
  unsigned u = __builtin_bit_cast(unsigned, f);
  unsigned r = (u + 0x7fffu + ((u >> 16) & 1u)) >> 16;
  return (ushort_t)r;
}

__device__ __forceinline__ void load_lds16(const void* g, void* l) {
  __builtin_amdgcn_global_load_lds((__attribute__((address_space(1))) void*)(g),
                                   (__attribute__((address_space(3))) void*)(l),
                                   16, 0, 0);
}

// bijective XCD-aware remap (m204 form) over a 3-D grid.
__device__ __forceinline__ void xcd_swizzle(int& bx, int& by, int& bz) {
  const int gx = gridDim.x, gy = gridDim.y, gz = gridDim.z;
  const int nwg = gx * gy * gz;
  const int orig = (bz * gy + by) * gx + bx;
  const int q = nwg >> 3, r = nwg & 7;
  const int x = orig & 7, i = orig >> 3;
  const int wg = (x < r ? x * (q + 1) : r * (q + 1) + (x - r) * q) + i;
  bx = wg % gx;
  const int t = wg / gx;
  by = t % gy;
  bz = t / gy;
}

// ---------------------------------------------------------------------------
// Op descriptor (shared by gemm_btm / gemm256m)
// ---------------------------------------------------------------------------
struct GOp {
  const ushort_t* A; const ushort_t* Bt;
  float* C; ushort_t* Cbf;
  const float* bias_col; const float* bias_row;
  const float* rmul; const float* cmul; const float* tau;
  float* rowsum;
  int rmulStride, cmulStride, rsStride, rsMode;
  int K, lda, ldb, ldc, flags;
  long long sA, sB, sC;
  int gx, gy, blkStart, pad;
};
struct GB { GOp op[4]; int nOps; int totBlk; };

// ---------------------------------------------------------------------------
// gemm_btm: multi-op 128x128 GEMM (gemm_bt engine + descriptor dispatch).
// 256 threads, 16KB LDS, VGPR ~80 -> 3 blocks/CU (cross-block latency hiding,
// the best-measured engine at these shapes). Flat grid + bijective XCD swz.
// ---------------------------------------------------------------------------
__global__ __launch_bounds__(256) void gemm_btm(GB gb) {
  __shared__ __align__(16) ushort_t As[128 * 32];
  __shared__ __align__(16) ushort_t Bs[128 * 32];

  int bid = blockIdx.x;
  {
    const int nwg = gb.totBlk;
    const int q = nwg >> 3, r = nwg & 7;
    const int x = bid & 7, i = bid >> 3;
    bid = (x < r ? x * (q + 1) : r * (q + 1) + (x - r) * q) + i;
  }
  int oi = 0;
#pragma unroll
  for (int k = 1; k < 4; k++)
    if (k < gb.nOps && bid >= gb.op[k].blkStart) oi = k;
  const GOp o = gb.op[oi];
  const int local = bid - o.blkStart;
  const int bx = local % o.gx;
  const int tt_ = local / o.gx;
  const int by = tt_ % o.gy;
  const int bz = tt_ / o.gy;

  const ushort_t* Ab = o.A + (size_t)bz * o.sA;
  const ushort_t* Bb = o.Bt + (size_t)bz * o.sB;
  const int lda = o.lda, ldb = o.ldb;
  const int tm   = by * 128;
  const int tn   = bx * 128;
  const int tid  = threadIdx.x;
  const int wave = tid >> 6;
  const int lane = tid & 63;
  const int wm   = (wave & 1) << 6;
  const int wn   = (wave >> 1) << 6;
  const int sr   = lane >> 2;
  const int cp   = lane & 3;
  const int sc   = (((cp - (sr >> 1)) & 3) << 3);
  const int fr   = lane & 15;
  const int fk   = ((((lane >> 4) + (fr >> 1)) & 3) << 3);

  floatx4 acc[4][4] = {};

  for (int k0 = 0; k0 < o.K; k0 += 32) {
    {
      const ushort_t* gA0 = Ab + (size_t)(tm + wave * 16 + sr) * lda + (k0 + sc);
      const ushort_t* gA1 = gA0 + (size_t)64 * lda;
      char* lA = (char*)As + wave * 1024;
      load_lds16(gA0, lA);
      load_lds16(gA1, lA + 4096);
      const ushort_t* gB0 = Bb + (size_t)(tn + wave * 16 + sr) * ldb + (k0 + sc);
      const ushort_t* gB1 = gB0 + (size_t)64 * ldb;
      char* lB = (char*)Bs + wave * 1024;
      load_lds16(gB0, lB);
      load_lds16(gB1, lB + 4096);
    }
    __syncthreads();
    s16x8 af[4], bfv[4];
#pragma unroll
    for (int i = 0; i < 4; i++)
      af[i] = *(const s16x8*)&As[(wm + i * 16 + fr) * 32 + fk];
#pragma unroll
    for (int j = 0; j < 4; j++)
      bfv[j] = *(const s16x8*)&Bs[(wn + j * 16 + fr) * 32 + fk];
#pragma unroll
    for (int i = 0; i < 4; i++)
#pragma unroll
      for (int j = 0; j < 4; j++)
        acc[i][j] = __builtin_amdgcn_mfma_f32_16x16x32_bf16(af[i], bfv[j], acc[i][j], 0, 0, 0);
    __syncthreads();
  }

  const float tv = o.tau ? o.tau[bz] : 0.f;
  float*   Cp  = o.C   ? o.C   + (size_t)bz * o.sC : nullptr;
  ushort_t* Cb = o.Cbf ? o.Cbf + (size_t)bz * o.sC : nullptr;
  float bcv[4], cmv[4];
#pragma unroll
  for (int j = 0; j < 4; j++) {
    const int col = tn + wn + j * 16 + (lane & 15);
    bcv[j] = o.bias_col ? o.bias_col[col] : 0.f;
    cmv[j] = o.cmul ? o.cmul[(size_t)bz * o.cmulStride + col] : 1.f;
  }
#pragma unroll
  for (int i = 0; i < 4; i++) {
#pragma unroll
    for (int r = 0; r < 4; r++) {
      const int row = tm + wm + i * 16 + (lane >> 4) * 4 + r;
      const float rm = o.rmul ? o.rmul[(size_t)bz * o.rmulStride + row] : 1.f;
      const float br = o.bias_row ? o.bias_row[row] : 0.f;
      float rsum = 0.f;
#pragma unroll
      for (int j = 0; j < 4; j++) {
        const int col = tn + wn + j * 16 + (lane & 15);
        float v;
        if (o.flags & 2) {
          v = acc[i][j][r] * (rm * cmv[j]) + bcv[j] + br;
        } else {
          v = (acc[i][j][r] + bcv[j] + br) * (rm * cmv[j]);
        }
        if (o.flags & 1) v = fmaxf(v, 0.f);
        if (o.tau) { float d = 1.0f - v; v = fmaxf(1.0f - tv * 0.25f * d * d, 0.f); }
        rsum += (o.rsMode == 2) ? v * v : v;
        if (Cp) Cp[(size_t)row * o.ldc + col] = v;
        if (Cb) Cb[(size_t)row * o.ldc + col] = f2b(v);
      }
      if (o.rsMode == 1 || o.rsMode == 2) {
        rsum += __shfl_xor(rsum, 1);
        rsum += __shfl_xor(rsum, 2);
        rsum += __shfl_xor(rsum, 4);
        rsum += __shfl_xor(rsum, 8);
        if ((lane & 15) == 0)
          atomicAdd(&o.rowsum[(size_t)bz * o.rsStride + row], rsum);
      }
    }
  }
}

// ---------------------------------------------------------------------------
// gemm256m: multi-op 256x256 GEMM (R6 schedule). Used ONLY for scores
// (256 blocks = exact machine fill; measured fastest engine for that op).
// ---------------------------------------------------------------------------
__global__ __launch_bounds__(512, 2) void gemm256m(GB gb) {
  __shared__ __align__(16) ushort_t lds[2][2][2][256][32];

  int bid = blockIdx.x;
  {
    const int nwg = gb.totBlk;
    const int q = nwg >> 3, r = nwg & 7;
    const int x = bid & 7, i = bid >> 3;
    bid = (x < r ? x * (q + 1) : r * (q + 1) + (x - r) * q) + i;
  }
  int oi = 0;
#pragma unroll
  for (int k = 1; k < 4; k++)
    if (k < gb.nOps && bid >= gb.op[k].blkStart) oi = k;
  const GOp o = gb.op[oi];
  const int local = bid - o.blkStart;
  const int bx = local % o.gx;
  const int tt_ = local / o.gx;
  const int by = tt_ % o.gy;
  const int bz = tt_ / o.gy;

  const ushort_t* Ab = o.A + (size_t)bz * o.sA;
  const ushort_t* Bb = o.Bt + (size_t)bz * o.sB;
  const int tm   = by * 256;
  const int tn   = bx * 256;
  const int tid  = threadIdx.x;
  const int wave = tid >> 6;
  const int lane = tid & 63;
  const int wm   = wave >> 2;
  const int wn   = wave & 3;

  const int s_r  = lane >> 2;
  const int s_cg = (((lane & 3) - (s_r >> 1)) & 3);
  const int f_r  = lane & 15;
  const int f_p  = ((((lane >> 4) + (f_r >> 1)) & 3) << 3);

  const int lda = o.lda, ldb = o.ldb;
  const int NTILES = o.K >> 6;

  floatx4 acc[8][4] = {};

#define STAGE256(tt, g, sl)                                                     \
  do {                                                                          \
    const int mat_ = (g) & 1, h_ = (g) >> 1;                                    \
    const ushort_t* src_ = mat_ ? Bb : Ab;                                      \
    const int ld_ = mat_ ? ldb : lda;                                           \
    const int tb_ = mat_ ? tn : tm;                                             \
    const int kofs_ = (tt) * 64 + h_ * 32 + s_cg * 8;                           \
    _Pragma("unroll")                                                           \
    for (int j_ = 0; j_ < 2; j_++) {                                            \
      const int slab_ = wave * 2 + j_;                                          \
      const ushort_t* gp_ = src_ + (size_t)(tb_ + slab_ * 16 + s_r) * ld_ + kofs_; \
      load_lds16(gp_, (void*)&lds[sl][mat_][h_][slab_ * 16][0]);                \
    }                                                                           \
  } while (0)

  STAGE256(0, 0, 0);
  STAGE256(0, 1, 0);
  STAGE256(0, 2, 0);
  STAGE256(0, 3, 0);
  STAGE256(1, 0, 1);
  STAGE256(1, 1, 1);
  asm volatile("s_waitcnt vmcnt(4)" ::: "memory");
  __builtin_amdgcn_s_barrier();

  for (int t = 0; t < NTILES; t++) {
    const int sl  = t & 1;
    const int sl1 = sl ^ 1;
    const int t1  = (t + 1 < NTILES) ? t + 1 : t;
    const int t2  = (t + 2 < NTILES) ? t + 2 : t;
    s16x8 a[8], b[4];

#pragma unroll
    for (int m = 0; m < 8; m++)
      a[m] = *(const s16x8*)&lds[sl][0][0][wm * 128 + m * 16 + f_r][f_p];
#pragma unroll
    for (int n = 0; n < 4; n++)
      b[n] = *(const s16x8*)&lds[sl][1][0][wn * 64 + n * 16 + f_r][f_p];
    STAGE256(t1, 2, sl1);
    __builtin_amdgcn_s_barrier();
    __builtin_amdgcn_s_setprio(1);
#pragma unroll
    for (int m = 0; m < 8; m++)
#pragma unroll
      for (int n = 0; n < 2; n++)
        acc[m][n] = __builtin_amdgcn_mfma_f32_16x16x32_bf16(a[m], b[n], acc[m][n], 0, 0, 0);
    __builtin_amdgcn_s_setprio(0);
    __builtin_amdgcn_s_barrier();

    STAGE256(t1, 3, sl1);
    __builtin_amdgcn_s_barrier();
    __builtin_amdgcn_s_setprio(1);
#pragma unroll
    for (int m = 0; m < 8; m++)
#pragma unroll
      for (int n = 2; n < 4; n++)
        acc[m][n] = __builtin_amdgcn_mfma_f32_16x16x32_bf16(a[m], b[n], acc[m][n], 0, 0, 0);
    __builtin_amdgcn_s_setprio(0);
    __builtin_amdgcn_s_barrier();

#pragma unroll
    for (int m = 0; m < 8; m++)
      a[m] = *(const s16x8*)&lds[sl][0][1][wm * 128 + m * 16 + f_r][f_p];
#pragma unroll
    for (int n = 0; n < 4; n++)
      b[n] = *(const s16x8*)&lds[sl][1][1][wn * 64 + n * 16 + f_r][f_p];
    STAGE256(t2, 0, sl);
    __builtin_amdgcn_s_barrier();
    __builtin_amdgcn_s_setprio(1);
#pragma unroll
    for (int m = 0; m < 8; m++)
#pragma unroll
      for (int n = 0; n < 2; n++)
        acc[m][n] = __builtin_amdgcn_mfma_f32_16x16x32_bf16(a[m], b[n], acc[m][n], 0, 0, 0);
    __builtin_amdgcn_s_setprio(0);
    __builtin_amdgcn_s_barrier();

    STAGE256(t2, 1, sl);
    __builtin_amdgcn_s_barrier();
    __builtin_amdgcn_s_setprio(1);
#pragma unroll
    for (int m = 0; m < 8; m++)
#pragma unroll
      for (int n = 2; n < 4; n++)
        acc[m][n] = __builtin_amdgcn_mfma_f32_16x16x32_bf16(a[m], b[n], acc[m][n], 0, 0, 0);
    __builtin_amdgcn_s_setprio(0);
    asm volatile("s_waitcnt vmcnt(4)" ::: "memory");
    __builtin_amdgcn_s_barrier();
  }
#undef STAGE256

  const float tv = o.tau ? o.tau[bz] : 0.f;
  float*   Cp  = o.C   ? o.C   + (size_t)bz * o.sC : nullptr;
  ushort_t* Cb = o.Cbf ? o.Cbf + (size_t)bz * o.sC : nullptr;
  float bcv[4], cmv[4];
#pragma unroll
  for (int n = 0; n < 4; n++) {
    const int col = tn + wn * 64 + n * 16 + (lane & 15);
    bcv[n] = o.bias_col ? o.bias_col[col] : 0.f;
    cmv[n] = o.cmul ? o.cmul[(size_t)bz * o.cmulStride + col] : 1.f;
  }
#pragma unroll
  for (int m = 0; m < 8; m++) {
#pragma unroll
    for (int r = 0; r < 4; r++) {
      const int row = tm + wm * 128 + m * 16 + (lane >> 4) * 4 + r;
      const float rm = o.rmul ? o.rmul[(size_t)bz * o.rmulStride + row] : 1.f;
      const float br = o.bias_row ? o.bias_row[row] : 0.f;
      float rsum = 0.f;
#pragma unroll
      for (int n = 0; n < 4; n++) {
        const int col = tn + wn * 64 + n * 16 + (lane & 15);
        float v;
        if (o.flags & 2) {
          v = acc[m][n][r] * (rm * cmv[n]) + bcv[n] + br;
        } else {
          v = (acc[m][n][r] + bcv[n] + br) * (rm * cmv[n]);
        }
        if (o.flags & 1) v = fmaxf(v, 0.f);
        if (o.tau) { float d = 1.0f - v; v = fmaxf(1.0f - tv * 0.25f * d * d, 0.f); }
        rsum += (o.rsMode == 2) ? v * v : v;
        if (Cp) Cp[(size_t)row * o.ldc + col] = v;
        if (Cb) Cb[(size_t)row * o.ldc + col] = f2b(v);
      }
      if (o.rsMode == 1 || o.rsMode == 2) {
        rsum += __shfl_xor(rsum, 1);
        rsum += __shfl_xor(rsum, 2);
        rsum += __shfl_xor(rsum, 4);
        rsum += __shfl_xor(rsum, 8);
        if ((lane & 15) == 0)
          atomicAdd(&o.rowsum[(size_t)bz * o.rsStride + row], rsum);
      }
    }
  }
}

// ---------------------------------------------------------------------------
// gemm_bt: single-op 128x128 kernel (MLP2, RF, ITab, context) + XCD swizzle
// ---------------------------------------------------------------------------
__global__ __launch_bounds__(256) void gemm_bt(
    const ushort_t* __restrict__ A, const ushort_t* __restrict__ Bt,
    float* __restrict__ C, ushort_t* __restrict__ Cbf,
    const float* __restrict__ bias_col, const float* __restrict__ bias_row,
    const float* __restrict__ rmul, int rmulStride,
    const float* __restrict__ cmul, int cmulStride,
    const float* __restrict__ tau,
    float* __restrict__ rowsum, int rsStride, int rsMode,
    int K, int lda, int ldb, int ldc,
    long long sA, long long sB, long long sC, int flags)
{
  __shared__ __align__(16) ushort_t As[128 * 32];
  __shared__ __align__(16) ushort_t Bs[128 * 32];

  int bx = blockIdx.x, by = blockIdx.y, bz = blockIdx.z;
  xcd_swizzle(bx, by, bz);
  const ushort_t* Ab = A + (size_t)bz * sA;
  const ushort_t* Bb = Bt + (size_t)bz * sB;
  const int tm   = by * 128;
  const int tn   = bx * 128;
  const int tid  = threadIdx.x;
  const int wave = tid >> 6;
  const int lane = tid & 63;
  const int wm   = (wave & 1) << 6;
  const int wn   = (wave >> 1) << 6;
  const int sr   = lane >> 2;
  const int cp   = lane & 3;
  const int sc   = (((cp - (sr >> 1)) & 3) << 3);
  const int fr   = lane & 15;
  const int fk   = ((((lane >> 4) + (fr >> 1)) & 3) << 3);

  floatx4 acc[4][4] = {};

  for (int k0 = 0; k0 < K; k0 += 32) {
    {
      const ushort_t* gA0 = Ab + (size_t)(tm + wave * 16 + sr) * lda + (k0 + sc);
      const ushort_t* gA1 = gA0 + (size_t)64 * lda;
      char* lA = (char*)As + wave * 1024;
      load_lds16(gA0, lA);
      load_lds16(gA1, lA + 4096);
      const ushort_t* gB0 = Bb + (size_t)(tn + wave * 16 + sr) * ldb + (k0 + sc);
      const ushort_t* gB1 = gB0 + (size_t)64 * ldb;
      char* lB = (char*)Bs + wave * 1024;
      load_lds16(gB0, lB);
      load_lds16(gB1, lB + 4096);
    }
    __syncthreads();
    s16x8 af[4], bfv[4];
#pragma unroll
    for (int i = 0; i < 4; i++)
      af[i] = *(const s16x8*)&As[(wm + i * 16 + fr) * 32 + fk];
#pragma unroll
    for (int j = 0; j < 4; j++)
      bfv[j] = *(const s16x8*)&Bs[(wn + j * 16 + fr) * 32 + fk];
#pragma unroll
    for (int i = 0; i < 4; i++)
#pragma unroll
      for (int j = 0; j < 4; j++)
        acc[i][j] = __builtin_amdgcn_mfma_f32_16x16x32_bf16(af[i], bfv[j], acc[i][j], 0, 0, 0);
    __syncthreads();
  }

  const float tv = tau ? tau[bz] : 0.f;
  float*   Cp  = C   ? C   + (size_t)bz * sC : nullptr;
  ushort_t* Cb = Cbf ? Cbf + (size_t)bz * sC : nullptr;
  float bcv[4], cmv[4];
#pragma unroll
  for (int j = 0; j < 4; j++) {
    const int col = tn + wn + j * 16 + (lane & 15);
    bcv[j] = bias_col ? bias_col[col] : 0.f;
    cmv[j] = cmul ? cmul[(size_t)bz * cmulStride + col] : 1.f;
  }
#pragma unroll
  for (int i = 0; i < 4; i++) {
#pragma unroll
    for (int r = 0; r < 4; r++) {
      const int row = tm + wm + i * 16 + (lane >> 4) * 4 + r;
      const float rm = rmul ? rmul[(size_t)bz * rmulStride + row] : 1.f;
      const float br = bias_row ? bias_row[row] : 0.f;
      float rsum = 0.f;
#pragma unroll
      for (int j = 0; j < 4; j++) {
        const int col = tn + wn + j * 16 + (lane & 15);
        float v;
        if (flags & 2) {
          v = acc[i][j][r] * (rm * cmv[j]) + bcv[j] + br;
        } else {
          v = (acc[i][j][r] + bcv[j] + br) * (rm * cmv[j]);
        }
        if (flags & 1) v = fmaxf(v, 0.f);
        if (tau) { float d = 1.0f - v; v = fmaxf(1.0f - tv * 0.25f * d * d, 0.f); }
        rsum += (rsMode == 2) ? v * v : v;
        if (Cp) Cp[(size_t)row * ldc + col] = v;
        if (Cb) Cb[(size_t)row * ldc + col] = f2b(v);
      }
      if (rsMode == 1 || rsMode == 2) {
        rsum += __shfl_xor(rsum, 1);
        rsum += __shfl_xor(rsum, 2);
        rsum += __shfl_xor(rsum, 4);
        rsum += __shfl_xor(rsum, 8);
        if ((lane & 15) == 0)
          atomicAdd(&rowsum[(size_t)bz * rsStride + row], rsum);
      }
    }
  }
}

// ---------------------------------------------------------------------------
// prep3: batched weight-product GEMMs (K=1024, bf16 out)
// ---------------------------------------------------------------------------
struct P3 { const ushort_t* A[3]; const ushort_t* Bt[3]; ushort_t* C[3]; int M[3]; };

__global__ __launch_bounds__(256) void prep3(P3 p) {
  __shared__ __align__(16) ushort_t As[128 * 32];
  __shared__ __align__(16) ushort_t Bs[128 * 32];
  const int z  = blockIdx.z;
  const int tm = blockIdx.y * 128;
  if (tm >= p.M[z]) return;
  const ushort_t* Ab = p.A[z];
  const ushort_t* Bb = p.Bt[z];
  ushort_t*       Cc = p.C[z];
  const int tn   = blockIdx.x * 128;
  const int tid  = threadIdx.x;
  const int wave = tid >> 6;
  const int lane = tid & 63;
  const int wm   = (wave & 1) << 6;
  const int wn   = (wave >> 1) << 6;
  const int sr   = lane >> 2;
  const int cp   = lane & 3;
  const int sc   = (((cp - (sr >> 1)) & 3) << 3);
  const int fr   = lane & 15;
  const int fk   = ((((lane >> 4) + (fr >> 1)) & 3) << 3);

  floatx4 acc[4][4] = {};

  for (int k0 = 0; k0 < Dd; k0 += 32) {
    {
      const ushort_t* gA0 = Ab + (size_t)(tm + wave * 16 + sr) * Dd + (k0 + sc);
      const ushort_t* gA1 = gA0 + (size_t)64 * Dd;
      char* lA = (char*)As + wave * 1024;
      load_lds16(gA0, lA);
      load_lds16(gA1, lA + 4096);
      const ushort_t* gB0 = Bb + (size_t)(tn + wave * 16 + sr) * Dd + (k0 + sc);
      const ushort_t* gB1 = gB0 + (size_t)64 * Dd;
      char* lB = (char*)Bs + wave * 1024;
      load_lds16(gB0, lB);
      load_lds16(gB1, lB + 4096);
    }
    __syncthreads();
    s16x8 af[4], bfv[4];
#pragma unroll
    for (int i = 0; i < 4; i++)
      af[i] = *(const s16x8*)&As[(wm + i * 16 + fr) * 32 + fk];
#pragma unroll
    for (int j = 0; j < 4; j++)
      bfv[j] = *(const s16x8*)&Bs[(wn + j * 16 + fr) * 32 + fk];
#pragma unroll
    for (int i = 0; i < 4; i++)
#pragma unroll
      for (int j = 0; j < 4; j++)
        acc[i][j] = __builtin_amdgcn_mfma_f32_16x16x32_bf16(af[i], bfv[j], acc[i][j], 0, 0, 0);
    __syncthreads();
  }

#pragma unroll
  for (int i = 0; i < 4; i++)
#pragma unroll
    for (int r = 0; r < 4; r++) {
      const int row = tm + wm + i * 16 + (lane >> 4) * 4 + r;
#pragma unroll
      for (int j = 0; j < 4; j++) {
        const int col = tn + wn + j * 16 + (lane & 15);
        Cc[(size_t)row * Dd + col] = f2b(acc[i][j][r]);
      }
    }
}

// ---------------------------------------------------------------------------
// small kernels
// ---------------------------------------------------------------------------
__global__ __launch_bounds__(256) void castbf(const float* __restrict__ in,
                                              ushort_t* __restrict__ out, int n4) {
  int i = blockIdx.x * 256 + threadIdx.x;
  if (i >= n4) return;
  float4 v = ((const float4*)in)[i];
  ushort4 o;
  o.x = f2b(v.x); o.y = f2b(v.y); o.z = f2b(v.z); o.w = f2b(v.w);
  ((ushort4*)out)[i] = o;
}

// 3-tensor cast in one launch: grid(8192, 3)
struct C3 { const float* in[3]; ushort_t* out[3]; };
__global__ __launch_bounds__(256) void castbf3(C3 p) {
  int z = blockIdx.y;
  int i = blockIdx.x * 256 + threadIdx.x;
  float4 v = ((const float4*)p.in[z])[i];
  ushort4 o;
  o.x = f2b(v.x); o.y = f2b(v.y); o.z = f2b(v.z); o.w = f2b(v.w);
  ((ushort4*)p.out[z])[i] = o;
}

struct TC4 { const float* in[4]; ushort_t* out[4]; };
__global__ __launch_bounds__(256) void tcast4(TC4 p) {
  __shared__ float t[32][33];
  int z = blockIdx.z;
  const float* in = p.in[z];
  ushort_t* out = p.out[z];
  int r0 = blockIdx.x * 32, c0 = blockIdx.y * 32;
  int x = threadIdx.x, y = threadIdx.y;
  for (int dy = 0; dy < 32; dy += 8)
    t[y + dy][x] = in[(size_t)(r0 + y + dy) * 1024 + c0 + x];
  __syncthreads();
  for (int dy = 0; dy < 32; dy += 8)
    out[(size_t)(c0 + y + dy) * 1024 + r0 + x] = f2b(t[x][y + dy]);
}

__global__ __launch_bounds__(256) void tcast(const float* __restrict__ in,
                                             ushort_t* __restrict__ out,
                                             int RrN, int Cc, int Cp) {
  __shared__ float t[32][33];
  int r0 = blockIdx.x * 32, c0 = blockIdx.y * 32;
  int x = threadIdx.x, y = threadIdx.y;
  for (int dy = 0; dy < 32; dy += 8) {
    int r = r0 + y + dy, c = c0 + x;
    t[y + dy][x] = (c < Cc) ? in[(size_t)r * Cc + c] : 0.f;
  }
  __syncthreads();
  for (int dy = 0; dy < 32; dy += 8) {
    int c = c0 + y + dy, r = r0 + x;
    if (c < Cp) out[(size_t)c * RrN + r] = f2b(t[x][y + dy]);
  }
}

__global__ __launch_bounds__(256) void rolenorm(const float* __restrict__ rm,
                                                ushort_t* __restrict__ rmn) {
  int r = blockIdx.x, tid = threadIdx.x;
  float4 v = ((const float4*)(rm + (size_t)r * 1024))[tid];
  float s = v.x * v.x + v.y * v.y + v.z * v.z + v.w * v.w;
#pragma unroll
  for (int m = 1; m < 64; m <<= 1) s += __shfl_xor(s, m);
  __shared__ float red[6];
  if ((tid & 63) == 0) red[tid >> 6] = s;
  __syncthreads();
  if (tid == 0) red[4] = 1.f / fmaxf(sqrtf(red[0] + red[1] + red[2] + red[3]), 1e-12f);
  __syncthreads();
  float inv = red[4];
  ushort4 o;
  o.x = f2b(v.x * inv); o.y = f2b(v.y * inv); o.z = f2b(v.z * inv); o.w = f2b(v.w * inv);
  ((ushort4*)(rmn + (size_t)r * 1024))[tid] = o;
}

__global__ __launch_bounds__(256) void rfn_kernel(const ushort_t* __restrict__ rmn,
                                                  const ushort_t* __restrict__ ftab,
                                                  ushort_t* __restrict__ RFnT) {
  int f = blockIdx.x;
  int t = threadIdx.x;
  int r = t >> 2, part = t & 3;
  const ushort_t* fr = ftab + (size_t)f * 1024 + part * 256;
  const ushort_t* rr = rmn + (size_t)r * 1024 + part * 256;
  float s = 0.f;
#pragma unroll 4
  for (int i = 0; i < 32; i++) {
    s16x8 a = *(const s16x8*)(fr + i * 8);
    s16x8 b = *(const s16x8*)(rr + i * 8);
#pragma unroll
    for (int j = 0; j < 8; j++) s += b2f((ushort_t)a[j]) * b2f((ushort_t)b[j]);
  }
  s += __shfl_xor(s, 1);
  s += __shfl_xor(s, 2);
  if (part == 0) RFnT[(size_t)f * 128 + r] = f2b(s);
}

__global__ __launch_bounds__(64) void foldbk(const ushort_t* __restrict__ ftab,
                                             const float* __restrict__ bk,
                                             float* __restrict__ bkF) {
  int j = blockIdx.x, lane = threadIdx.x;
  const ushort_t* row = ftab + (size_t)j * 1024 + lane * 16;
  const float* bp = bk + lane * 16;
  float s = 0.f;
#pragma unroll
  for (int i = 0; i < 2; i++) {
    s16x8 a = *(const s16x8*)(row + i * 8);
#pragma unroll
    for (int e = 0; e < 8; e++) s += b2f((ushort_t)a[e]) * bp[i * 8 + e];
  }
#pragma unroll
  for (int m = 1; m < 64; m <<= 1) s += __shfl_xor(s, m);
  if (lane == 0) bkF[j] = s;
}

__global__ __launch_bounds__(256) void foldbh(const float* __restrict__ Wr1,
                                              const float* __restrict__ bk,
                                              const float* __restrict__ br1,
                                              float* __restrict__ bh) {
  int h = blockIdx.x * 256 + threadIdx.x;
  float s = br1[h];
  for (int d = 0; d < 1024; d++) s += bk[d] * Wr1[(size_t)d * Hh + h];
  bh[h] = s;
}

__global__ __launch_bounds__(256) void foldbvo(const float* __restrict__ Wo,
                                               const float* __restrict__ bv,
                                               const float* __restrict__ bo,
                                               float* __restrict__ bvo) {
  int d = blockIdx.x * 256 + threadIdx.x;
  float s = bo[d];
  for (int e = 0; e < 1024; e++) s += bv[e] * Wo[(size_t)e * 1024 + d];
  bvo[d] = s;
}

__global__ __launch_bounds__(256) void invnorm_surprise(const float* __restrict__ ssq,
                                                        float* __restrict__ invn,
                                                        float* __restrict__ ssum) {
  int row = blockIdx.x * 256 + threadIdx.x;
  float nrm = sqrtf(ssq[row]);
  invn[row] = 1.f / fmaxf(nrm, 1e-12f);
  float t = nrm;
#pragma unroll
  for (int m = 1; m < 64; m <<= 1) t += __shfl_xor(t, m);
  if ((threadIdx.x & 63) == 0) atomicAdd(&ssum[row >> 11], t);
}

__global__ __launch_bounds__(256) void invnorm(const float* __restrict__ ssq,
                                               float* __restrict__ invn) {
  int row = blockIdx.x * 256 + threadIdx.x;
  invn[row] = 1.f / fmaxf(sqrtf(ssq[row]), 1e-12f);
}

__global__ __launch_bounds__(256) void invrowsum(const float* __restrict__ rs,
                                                 float* __restrict__ inv) {
  int row = blockIdx.x * 256 + threadIdx.x;
  inv[row] = 1.f / fmaxf(rs[row], 1e-9f);
}

__global__ void finalize_astro(const float* __restrict__ ssum, const float* __restrict__ astro,
                               const float* __restrict__ ascale, float* __restrict__ tau,
                               float* __restrict__ outTail) {
  int b = threadIdx.x;
  if (b < Bq) {
    float mean = ssum[b] * (1.f / (32.f * 2048.f));
    float ns = 0.95f * astro[b] + 0.05f * mean;
    tau[b] = fmaxf(1.f + ascale[0] * ns, 0.001f);
    outTail[b] = ns;
  }
}

__global__ __launch_bounds__(256) void softmax64(const float* __restrict__ logits,
                                                 ushort_t* __restrict__ out) {
  int row = blockIdx.x * 4 + (threadIdx.x >> 6);
  int lane = threadIdx.x & 63;
  float x = logits[(size_t)row * 128 + lane];
  float m = x;
#pragma unroll
  for (int s = 1; s < 64; s <<= 1) m = fmaxf(m, __shfl_xor(m, s));
  float e = expf(x - m);
  float sum = e;
#pragma unroll
  for (int s = 1; s < 64; s <<= 1) sum += __shfl_xor(sum, s);
  out[(size_t)row * 64 + lane] = f2b(e / sum);
}

__global__ __launch_bounds__(256) void gen_ftab(ushort_t* __restrict__ ftab) {
  const float TW = 6.283185307179586f / 1024.f;
  int idx = blockIdx.x * 256 + threadIdx.x;
  int j = idx >> 10, k = idx & 1023;
  int f = j <= 512 ? j : j - 512;
  float th = (float)((f * k) & 1023) * TW;
  float sv, cv; sincosf(th, &sv, &cv);
  ftab[idx] = f2b(j <= 512 ? cv : -sv);
}

// itab[n][j] = s(j) * ftab[j][n]; s(j) = 2^-10 (j==0||j==512) else 2^-9.
// pow2 scale commutes with bf16 rounding -> bit-identical to sincos version.
__global__ __launch_bounds__(256) void titab(const ushort_t* __restrict__ ftab,
                                             ushort_t* __restrict__ itab) {
  __shared__ float t[32][33];
  int j0 = blockIdx.x * 32, n0 = blockIdx.y * 32;
  int x = threadIdx.x, y = threadIdx.y;
  for (int dy = 0; dy < 32; dy += 8) {
    int j = j0 + y + dy;
    float s = (j == 0 || j == 512) ? (1.f / 1024.f) : (2.f / 1024.f);
    t[y + dy][x] = b2f(ftab[(size_t)j * 1024 + n0 + x]) * s;
  }
  __syncthreads();
  for (int dy = 0; dy < 32; dy += 8)
    itab[(size_t)(n0 + y + dy) * 1024 + j0 + x] = f2b(t[x][y + dy]);
}

__global__ __launch_bounds__(256) void fftmul(const ushort_t* __restrict__ KF,
                                              const ushort_t* __restrict__ RF,
                                              ushort_t* __restrict__ P) {
  int idx = blockIdx.x * 256 + threadIdx.x;
  int t = idx >> 9;
  int j = idx & 511;
  size_t base = (size_t)t * FQ;
  if (j == 0) {
    P[base]       = f2b(b2f(KF[base]) * b2f(RF[base]));
    P[base + 512] = f2b(b2f(KF[base + 512]) * b2f(RF[base + 512]));
  } else {
    float a = b2f(KF[base + j]), b = b2f(KF[base + 512 + j]);
    float c = b2f(RF[base + j]), d = b2f(RF[base + 512 + j]);
    P[base + j]       = f2b(a * c - b * d);
    P[base + 512 + j] = f2b(a * d + b * c);
  }
}

// ---------------------------------------------------------------------------
// workspace layout (bytes, 256-aligned)
// ---------------------------------------------------------------------------
static constexpr size_t OFF_RS    = 0;
static constexpr size_t OFF_SSQQ  = 32768;
static constexpr size_t OFF_SSQK  = 65536;
static constexpr size_t OFF_INVQ  = 98304;
static constexpr size_t OFF_INVK  = 131072;
static constexpr size_t OFF_INVRS = 163840;
static constexpr size_t OFF_SSUM  = 196608;
static constexpr size_t OFF_TAU   = 196864;
static constexpr size_t OFF_WQT   = 197120;
static constexpr size_t OFF_WKB   = OFF_WQT  + 2097152;
static constexpr size_t OFF_WVB   = OFF_WKB  + 2097152;
static constexpr size_t OFF_WOT   = OFF_WVB  + 2097152;
static constexpr size_t OFF_WR1T  = OFF_WOT  + 2097152;
static constexpr size_t OFF_WR2T  = OFF_WR1T + 1048576;
static constexpr size_t OFF_RMN   = OFF_WR2T + 131072;
static constexpr size_t OFF_FTAB  = OFF_RMN  + 131072;
static constexpr size_t OFF_ITAB  = OFF_FTAB + 2097152;
static constexpr size_t OFF_RFNT  = OFF_ITAB + 2097152;
static constexpr size_t OFF_B1    = OFF_RFNT + 262144;
static constexpr size_t OFF_B2    = OFF_B1   + 16777216;
static constexpr size_t OFF_B3    = OFF_B2   + 16777216;
static constexpr size_t OFF_B4    = OFF_B3   + 16777216;
static constexpr size_t OFF_B5    = OFF_B4   + 16777216;
static constexpr size_t OFF_B6    = OFF_B5   + 16777216;
static constexpr size_t OFF_B7    = OFF_B6   + 16777216;
static constexpr size_t OFF_HID   = OFF_B7   + 16777216;
static constexpr size_t OFF_LOGI  = OFF_HID  + 8388608;
static constexpr size_t OFF_RW    = OFF_LOGI + 4194304;
static constexpr size_t OFF_SB    = OFF_RW   + 1048576;
static constexpr size_t WS_NEEDED = OFF_SB   + 33554432;
static constexpr size_t OFF_WKF   = OFF_B6;
static constexpr size_t OFF_WOV   = OFF_B6 + 2097152;
static constexpr size_t OFF_WKR1  = OFF_B6 + 4194304;
static constexpr size_t OFF_BKF   = OFF_B6 + 5242880;
static constexpr size_t OFF_BH    = OFF_B6 + 5247232;
static constexpr size_t OFF_BVO   = OFF_B6 + 5249536;

static inline void launch_gemm(hipStream_t s, const ushort_t* A, const ushort_t* Bt,
                               float* Cf, ushort_t* Cb,
                               const float* bias_col, const float* bias_row,
                               const float* rmul, int rmulStride,
                               const float* cmul, int cmulStride,
                               const float* tau, float* rowsum, int rsStride, int rsMode,
                               int M, int N, int K, int lda, int ldb, int ldc,
                               long long sA, long long sB, long long sC, int Z, int flags) {
  dim3 g(N / 128, M / 128, Z), b(256);
  gemm_bt<<<g, b, 0, s>>>(A, Bt, Cf, Cb, bias_col, bias_row, rmul, rmulStride,
                          cmul, cmulStride, tau, rowsum, rsStride, rsMode,
                          K, lda, ldb, ldc, sA, sB, sC, flags);
}

static inline GOp mkop(const ushort_t* A, const ushort_t* Bt, float* Cf, ushort_t* Cb,
                       const float* bias_col, const float* rmul, int rmulStride,
                       const float* cmul, int cmulStride, const float* tau,
                       float* rowsum, int rsStride, int rsMode,
                       int M, int N, int K, int lda, int ldb, int ldc,
                       long long sA, long long sB, long long sC, int flags,
                       int blkStart, int tile) {
  GOp o;
  o.A = A; o.Bt = Bt; o.C = Cf; o.Cbf = Cb;
  o.bias_col = bias_col; o.bias_row = nullptr;
  o.rmul = rmul; o.cmul = cmul; o.tau = tau; o.rowsum = rowsum;
  o.rmulStride = rmulStride; o.cmulStride = cmulStride;
  o.rsStride = rsStride; o.rsMode = rsMode;
  o.K = K; o.lda = lda; o.ldb = ldb; o.ldc = ldc; o.flags = flags;
  o.sA = sA; o.sB = sB; o.sC = sC;
  o.gx = N / tile; o.gy = M / tile; o.blkStart = blkStart; o.pad = 0;
  return o;
}

extern "C" void kernel_launch(void* const* d_in, const int* in_sizes, int n_in,
                              void* d_out, int out_size, void* d_ws, size_t ws_size,
                              hipStream_t stream) {
  (void)in_sizes; (void)n_in; (void)out_size;
  if (ws_size < WS_NEEDED) return;

  const float* q_in  = (const float*)d_in[0];
  const float* k_in  = (const float*)d_in[1];
  const float* v_in  = (const float*)d_in[2];
  const float* astro = (const float*)d_in[3];
  const float* Wq    = (const float*)d_in[4];
  const float* bq    = (const float*)d_in[5];
  const float* Wk    = (const float*)d_in[6];
  const float* bk    = (const float*)d_in[7];
  const float* Wv    = (const float*)d_in[8];
  const float* bv    = (const float*)d_in[9];
  const float* Wo    = (const float*)d_in[10];
  const float* bo    = (const float*)d_in[11];
  const float* roleM = (const float*)d_in[12];
  const float* Wr1   = (const float*)d_in[13];
  const float* br1   = (const float*)d_in[14];
  const float* Wr2   = (const float*)d_in[15];
  const float* ascl  = (const float*)d_in[16];

  char* ws = (char*)d_ws;
  float*    rowsumS = (float*)(ws + OFF_RS);
  float*    ssqQ    = (float*)(ws + OFF_SSQQ);
  float*    ssqK    = (float*)(ws + OFF_SSQK);
  float*    invQ    = (float*)(ws + OFF_INVQ);
  float*    invK    = (float*)(ws + OFF_INVK);
  float*    invRS   = (float*)(ws + OFF_INVRS);
  float*    ssum    = (float*)(ws + OFF_SSUM);
  float*    tau     = (float*)(ws + OFF_TAU);
  ushort_t* WqT  = (ushort_t*)(ws + OFF_WQT);
  ushort_t* Wkb  = (ushort_t*)(ws + OFF_WKB);
  ushort_t* Wvb  = (ushort_t*)(ws + OFF_WVB);
  ushort_t* WoT  = (ushort_t*)(ws + OFF_WOT);
  ushort_t* Wr1T = (ushort_t*)(ws + OFF_WR1T);
  ushort_t* Wr2T = (ushort_t*)(ws + OFF_WR2T);
  ushort_t* rmn  = (ushort_t*)(ws + OFF_RMN);
  ushort_t* FTab = (ushort_t*)(ws + OFF_FTAB);
  ushort_t* ITab = (ushort_t*)(ws + OFF_ITAB);
  ushort_t* RFnT = (ushort_t*)(ws + OFF_RFNT);
  ushort_t* qbf  = (ushort_t*)(ws + OFF_B1);   // dead after mergeA
  ushort_t* kbraw= (ushort_t*)(ws + OFF_B1);   // written by ITab GEMM
  ushort_t* kinb = (ushort_t*)(ws + OFF_B2);
  ushort_t* RF   = (ushort_t*)(ws + OFF_B2);
  ushort_t* vinb = (ushort_t*)(ws + OFF_B3);
  ushort_t* Pb   = (ushort_t*)(ws + OFF_B3);
  ushort_t* qraw = (ushort_t*)(ws + OFF_B4);
  ushort_t* KF   = (ushort_t*)(ws + OFF_B5);
  ushort_t* WkF  = (ushort_t*)(ws + OFF_WKF);
  ushort_t* Wov  = (ushort_t*)(ws + OFF_WOV);
  ushort_t* WkR1 = (ushort_t*)(ws + OFF_WKR1);
  float*    bkF  = (float*)(ws + OFF_BKF);
  float*    bh   = (float*)(ws + OFF_BH);
  float*    bvo  = (float*)(ws + OFF_BVO);
  ushort_t* vT   = (ushort_t*)(ws + OFF_B7);
  ushort_t* hid  = (ushort_t*)(ws + OFF_HID);
  float*    logi = (float*)(ws + OFF_LOGI);
  ushort_t* rw   = (ushort_t*)(ws + OFF_RW);
  ushort_t* Sb   = (ushort_t*)(ws + OFF_SB);
  float*    out  = (float*)d_out;

  // 0. zero accumulators
  hipMemsetAsync(ws, 0, OFF_SSUM + 256, stream);

  // 1. weight prep + tables
  TC4 tc4;
  tc4.in[0] = Wq; tc4.out[0] = WqT;
  tc4.in[1] = Wo; tc4.out[1] = WoT;
  tc4.in[2] = Wq; tc4.out[2] = WqT;
  tc4.in[3] = Wq; tc4.out[3] = WqT;
  tcast4<<<dim3(32, 32, 2), dim3(32, 8), 0, stream>>>(tc4);
  castbf<<<1024, 256, 0, stream>>>(Wk, Wkb, 262144);
  castbf<<<1024, 256, 0, stream>>>(Wv, Wvb, 262144);
  tcast<<<dim3(32, 16), dim3(32, 8), 0, stream>>>(Wr1, Wr1T, 1024, 512, 512);
  tcast<<<dim3(16, 4),  dim3(32, 8), 0, stream>>>(Wr2, Wr2T, 512, 64, 128);
  rolenorm<<<64, 256, 0, stream>>>(roleM, rmn);
  gen_ftab<<<(FQ * 1024) / 256, 256, 0, stream>>>(FTab);
  titab<<<dim3(32, 32), dim3(32, 8), 0, stream>>>(FTab, ITab);
  rfn_kernel<<<FQ, 256, 0, stream>>>(rmn, FTab, RFnT);

  P3 p3;
  p3.A[0] = FTab; p3.Bt[0] = Wkb; p3.C[0] = WkF;  p3.M[0] = 1024;
  p3.A[1] = WoT;  p3.Bt[1] = Wvb; p3.C[1] = Wov;  p3.M[1] = 1024;
  p3.A[2] = Wr1T; p3.Bt[2] = Wkb; p3.C[2] = WkR1; p3.M[2] = 512;
  prep3<<<dim3(8, 8, 3), 256, 0, stream>>>(p3);
  foldbk<<<1024, 64, 0, stream>>>(FTab, bk, bkF);
  foldbh<<<Hh / 256, 256, 0, stream>>>(Wr1, bk, br1, bh);
  foldbvo<<<Dd / 256, 256, 0, stream>>>(Wo, bv, bo, bvo);

  // 2. input casts (one launch)
  C3 c3;
  c3.in[0] = q_in; c3.out[0] = qbf;
  c3.in[1] = k_in; c3.out[1] = kinb;
  c3.in[2] = v_in; c3.out[2] = vinb;
  castbf3<<<dim3(8192, 3), 256, 0, stream>>>(c3);

  // 3. mergeA: {Q-proj, KF, Vw^T, MLP1} on gemm_btm (1792 blocks, 3/CU)
  {
    GB gb;
    gb.op[0] = mkop(qbf, WqT, nullptr, qraw, bq, nullptr, 0, nullptr, 0, nullptr,
                    ssqQ, 0, 2, NT, Dd, Dd, Dd, Dd, Dd, 0, 0, 0, 0, 0, 128);       // 512
    gb.op[1] = mkop(kinb, WkF, nullptr, KF, bkF, nullptr, 0, nullptr, 0, nullptr,
                    nullptr, 0, 0, NT, FQ, Dd, Dd, Dd, FQ, 0, 0, 0, 0, 512, 128);  // 512
    gb.op[2] = mkop(Wov, vinb, nullptr, vT, nullptr, nullptr, 0, nullptr, 0, nullptr,
                    nullptr, 0, 0, Dd, NT, Dd, Dd, Dd, NT, 0, 0, 0, 0, 1024, 128); // 512
    gb.op[3] = mkop(kinb, WkR1, nullptr, hid, bh, nullptr, 0, nullptr, 0, nullptr,
                    nullptr, 0, 0, NT, Hh, Dd, Dd, Dd, Hh, 0, 0, 0, 1 /*relu*/, 1536, 128); // 256
    gb.nOps = 4; gb.totBlk = 1792;
    gemm_btm<<<dim3(1792), dim3(256), 0, stream>>>(gb);
  }
  invnorm_surprise<<<NT / 256, 256, 0, stream>>>(ssqQ, invQ, ssum);
  finalize_astro<<<1, 64, 0, stream>>>(ssum, astro, ascl, tau, out + (size_t)NT * Dd);

  // 4. role path tail: MLP2 -> softmax -> RF
  launch_gemm(stream, hid, Wr2T, logi, nullptr, nullptr, nullptr,
              nullptr, 0, nullptr, 0, nullptr, nullptr, 0, 0,
              NT, 128, Hh, Hh, Hh, 128, 0, 0, 0, 1, 0);
  softmax64<<<NT / 4, 256, 0, stream>>>(logi, rw);
  launch_gemm(stream, rw, RFnT, nullptr, RF, nullptr, nullptr,
              nullptr, 0, nullptr, 0, nullptr, nullptr, 0, 0,
              NT, FQ, Rr_, Rr_, 128, FQ, 0, 0, 0, 1, 0);

  // 5. pointwise bind + inverse DFT (+sumsq)
  fftmul<<<(NT * 512) / 256, 256, 0, stream>>>(KF, RF, Pb);
  launch_gemm(stream, Pb, ITab, nullptr, kbraw, nullptr, nullptr,
              nullptr, 0, nullptr, 0, nullptr, ssqK, 0, 2,
              NT, Dd, FQ, FQ, FQ, Dd, 0, 0, 0, 1, 0);
  invnorm<<<NT / 256, 256, 0, stream>>>(ssqK, invK);

  // 6. attention scores on gemm256m (256 blocks fills chip; best engine here)
  {
    GB gb;
    GOp o = mkop(qraw, kbraw, nullptr, Sb, nullptr, invQ, Tq, invK, Tq, tau,
                 rowsumS, Tq, 1, Tq, Tq, Dd, Dd, Dd, Tq,
                 (long long)Tq * Dd, (long long)Tq * Dd, (long long)Tq * Tq, 0, 0, 256);
    gb.op[0] = o; gb.op[1] = o; gb.op[2] = o; gb.op[3] = o;
    gb.nOps = 1; gb.totBlk = 256;
    gemm256m<<<dim3(256), dim3(512), 0, stream>>>(gb);
  }
  invrowsum<<<NT / 256, 256, 0, stream>>>(rowsumS, invRS);

  // 7. context -> out on gemm_bt (512 blocks)
  launch_gemm(stream, Sb, vT, out, nullptr, bvo, nullptr,
              invRS, Tq, nullptr, 0, nullptr, nullptr, 0, 0,
              Tq, Dd, Tq, Tq, NT, Dd,
              (long long)Tq * Tq, (long long)Tq, (long long)Tq * Dd, Bq, 2 /*scale-then-bias*/);
}

// Round 7
// 637.513 us; speedup vs baseline: 1.2795x; 1.0924x over previous
//
#include <hip/hip_runtime.h>
#include <stdint.h>

// ---------------------------------------------------------------------------
// AstroSymbolicEpisodicLayer  (B=4, TQ=TK=2048, D=1024, R=64, H=512)
// R10: non-GEMM-tail round (engines untouched; per-CU rate is invariant).
//  * prep1: ONE dispatcher launch for all independent prep (ftab, weight
//    casts/transposes, rolenorm, q/k/v input casts) - 33408 blocks.
//  * prep2: ONE dispatcher launch for stage-2 prep (titab, rfn, foldbk,
//    PARALLELIZED foldbh/foldbvo via atomics, prep3) - 2592 blocks.
//  * mlp2sm: fused MLP2+softmax (wave-per-row dot K=512 + in-wave softmax);
//    kills the 64-block MLP2 GEMM, softmax64, and the logi buffer.
//  * epilogue flags: 4 = cmul holds sumsq (apply rsqrt), 8 = rmul holds raw
//    rowsum (apply reciprocal) - kills invnorm + invrowsum launches.
// Launch count 25 -> 12. Carries R4 folds, R6 gemm256 schedule, R9 engine
// assignment (mergeA on gemm_btm 1792 blocks, scores on gemm256m 256 blocks).
// ---------------------------------------------------------------------------

#define Bq 4
#define Tq 2048
#define Dd 1024
#define NT 8192      // B*T
#define Hh 512
#define Rr_ 64
#define FQ 1024      // packed rfft spectrum width: re(0..512) | im(1..511)

typedef unsigned short ushort_t;
typedef short s16x8 __attribute__((ext_vector_type(8)));
typedef float floatx4 __attribute__((ext_vector_type(4)));

__device__ __forceinline__ float b2f(ushort_t s) {
  unsigned u = (unsigned)s << 16;
  return __builtin_bit_cast(float, u);
}
__device__ __forceinline__ ushort_t f2b(float f) {
  unsigned u = __builtin_bit_cast(unsigned, f);
  unsigned r = (u + 0x7fffu + ((u >> 16) & 1u)) >> 16;
  return (ushort_t)r;
}

__device__ __forceinline__ void load_lds16(const void* g, void* l) {
  __builtin_amdgcn_global_load_lds((__attribute__((address_space(1))) void*)(g),
                                   (__attribute__((address_space(3))) void*)(l),
                                   16, 0, 0);
}

// bijective XCD-aware remap (m204 form) over a 3-D grid.
__device__ __forceinline__ void xcd_swizzle(int& bx, int& by, int& bz) {
  const int gx = gridDim.x, gy = gridDim.y, gz = gridDim.z;
  const int nwg = gx * gy * gz;
  const int orig = (bz * gy + by) * gx + bx;
  const int q = nwg >> 3, r = nwg & 7;
  const int x = orig & 7, i = orig >> 3;
  const int wg = (x < r ? x * (q + 1) : r * (q + 1) + (x - r) * q) + i;
  bx = wg % gx;
  const int t = wg / gx;
  by = t % gy;
  bz = t / gy;
}

// ---------------------------------------------------------------------------
// Op descriptor (shared by gemm_btm / gemm256m)
// flags: 1=relu, 2=scale-then-bias, 4=cmul-is-sumsq(rsqrt), 8=rmul-is-rowsum(rcp)
// ---------------------------------------------------------------------------
struct GOp {
  const ushort_t* A; const ushort_t* Bt;
  float* C; ushort_t* Cbf;
  const float* bias_col; const float* bias_row;
  const float* rmul; const float* cmul; const float* tau;
  float* rowsum;
  int rmulStride, cmulStride, rsStride, rsMode;
  int K, lda, ldb, ldc, flags;
  long long sA, sB, sC;
  int gx, gy, blkStart, pad;
};
struct GB { GOp op[4]; int nOps; int totBlk; };

// ---------------------------------------------------------------------------
// gemm_btm: multi-op 128x128 GEMM. 256 threads, 16KB LDS, ~3 blocks/CU.
// ---------------------------------------------------------------------------
__global__ __launch_bounds__(256) void gemm_btm(GB gb) {
  __shared__ __align__(16) ushort_t As[128 * 32];
  __shared__ __align__(16) ushort_t Bs[128 * 32];

  int bid = blockIdx.x;
  {
    const int nwg = gb.totBlk;
    const int q = nwg >> 3, r = nwg & 7;
    const int x = bid & 7, i = bid >> 3;
    bid = (x < r ? x * (q + 1) : r * (q + 1) + (x - r) * q) + i;
  }
  int oi = 0;
#pragma unroll
  for (int k = 1; k < 4; k++)
    if (k < gb.nOps && bid >= gb.op[k].blkStart) oi = k;
  const GOp o = gb.op[oi];
  const int local = bid - o.blkStart;
  const int bx = local % o.gx;
  const int tt_ = local / o.gx;
  const int by = tt_ % o.gy;
  const int bz = tt_ / o.gy;

  const ushort_t* Ab = o.A + (size_t)bz * o.sA;
  const ushort_t* Bb = o.Bt + (size_t)bz * o.sB;
  const int lda = o.lda, ldb = o.ldb;
  const int tm   = by * 128;
  const int tn   = bx * 128;
  const int tid  = threadIdx.x;
  const int wave = tid >> 6;
  const int lane = tid & 63;
  const int wm   = (wave & 1) << 6;
  const int wn   = (wave >> 1) << 6;
  const int sr   = lane >> 2;
  const int cp   = lane & 3;
  const int sc   = (((cp - (sr >> 1)) & 3) << 3);
  const int fr   = lane & 15;
  const int fk   = ((((lane >> 4) + (fr >> 1)) & 3) << 3);

  floatx4 acc[4][4] = {};

  for (int k0 = 0; k0 < o.K; k0 += 32) {
    {
      const ushort_t* gA0 = Ab + (size_t)(tm + wave * 16 + sr) * lda + (k0 + sc);
      const ushort_t* gA1 = gA0 + (size_t)64 * lda;
      char* lA = (char*)As + wave * 1024;
      load_lds16(gA0, lA);
      load_lds16(gA1, lA + 4096);
      const ushort_t* gB0 = Bb + (size_t)(tn + wave * 16 + sr) * ldb + (k0 + sc);
      const ushort_t* gB1 = gB0 + (size_t)64 * ldb;
      char* lB = (char*)Bs + wave * 1024;
      load_lds16(gB0, lB);
      load_lds16(gB1, lB + 4096);
    }
    __syncthreads();
    s16x8 af[4], bfv[4];
#pragma unroll
    for (int i = 0; i < 4; i++)
      af[i] = *(const s16x8*)&As[(wm + i * 16 + fr) * 32 + fk];
#pragma unroll
    for (int j = 0; j < 4; j++)
      bfv[j] = *(const s16x8*)&Bs[(wn + j * 16 + fr) * 32 + fk];
#pragma unroll
    for (int i = 0; i < 4; i++)
#pragma unroll
      for (int j = 0; j < 4; j++)
        acc[i][j] = __builtin_amdgcn_mfma_f32_16x16x32_bf16(af[i], bfv[j], acc[i][j], 0, 0, 0);
    __syncthreads();
  }

  const float tv = o.tau ? o.tau[bz] : 0.f;
  float*   Cp  = o.C   ? o.C   + (size_t)bz * o.sC : nullptr;
  ushort_t* Cb = o.Cbf ? o.Cbf + (size_t)bz * o.sC : nullptr;
  float bcv[4], cmv[4];
#pragma unroll
  for (int j = 0; j < 4; j++) {
    const int col = tn + wn + j * 16 + (lane & 15);
    bcv[j] = o.bias_col ? o.bias_col[col] : 0.f;
    cmv[j] = o.cmul ? o.cmul[(size_t)bz * o.cmulStride + col] : 1.f;
    if (o.flags & 4) cmv[j] = 1.f / fmaxf(sqrtf(cmv[j]), 1e-12f);
  }
#pragma unroll
  for (int i = 0; i < 4; i++) {
#pragma unroll
    for (int r = 0; r < 4; r++) {
      const int row = tm + wm + i * 16 + (lane >> 4) * 4 + r;
      float rm = o.rmul ? o.rmul[(size_t)bz * o.rmulStride + row] : 1.f;
      if (o.flags & 8) rm = 1.f / fmaxf(rm, 1e-9f);
      const float br = o.bias_row ? o.bias_row[row] : 0.f;
      float rsum = 0.f;
#pragma unroll
      for (int j = 0; j < 4; j++) {
        const int col = tn + wn + j * 16 + (lane & 15);
        float v;
        if (o.flags & 2) {
          v = acc[i][j][r] * (rm * cmv[j]) + bcv[j] + br;
        } else {
          v = (acc[i][j][r] + bcv[j] + br) * (rm * cmv[j]);
        }
        if (o.flags & 1) v = fmaxf(v, 0.f);
        if (o.tau) { float d = 1.0f - v; v = fmaxf(1.0f - tv * 0.25f * d * d, 0.f); }
        rsum += (o.rsMode == 2) ? v * v : v;
        if (Cp) Cp[(size_t)row * o.ldc + col] = v;
        if (Cb) Cb[(size_t)row * o.ldc + col] = f2b(v);
      }
      if (o.rsMode == 1 || o.rsMode == 2) {
        rsum += __shfl_xor(rsum, 1);
        rsum += __shfl_xor(rsum, 2);
        rsum += __shfl_xor(rsum, 4);
        rsum += __shfl_xor(rsum, 8);
        if ((lane & 15) == 0)
          atomicAdd(&o.rowsum[(size_t)bz * o.rsStride + row], rsum);
      }
    }
  }
}

// ---------------------------------------------------------------------------
// gemm256m: multi-op 256x256 GEMM (R6 schedule). Used ONLY for scores.
// ---------------------------------------------------------------------------
__global__ __launch_bounds__(512, 2) void gemm256m(GB gb) {
  __shared__ __align__(16) ushort_t lds[2][2][2][256][32];

  int bid = blockIdx.x;
  {
    const int nwg = gb.totBlk;
    const int q = nwg >> 3, r = nwg & 7;
    const int x = bid & 7, i = bid >> 3;
    bid = (x < r ? x * (q + 1) : r * (q + 1) + (x - r) * q) + i;
  }
  int oi = 0;
#pragma unroll
  for (int k = 1; k < 4; k++)
    if (k < gb.nOps && bid >= gb.op[k].blkStart) oi = k;
  const GOp o = gb.op[oi];
  const int local = bid - o.blkStart;
  const int bx = local % o.gx;
  const int tt_ = local / o.gx;
  const int by = tt_ % o.gy;
  const int bz = tt_ / o.gy;

  const ushort_t* Ab = o.A + (size_t)bz * o.sA;
  const ushort_t* Bb = o.Bt + (size_t)bz * o.sB;
  const int tm   = by * 256;
  const int tn   = bx * 256;
  const int tid  = threadIdx.x;
  const int wave = tid >> 6;
  const int lane = tid & 63;
  const int wm   = wave >> 2;
  const int wn   = wave & 3;

  const int s_r  = lane >> 2;
  const int s_cg = (((lane & 3) - (s_r >> 1)) & 3);
  const int f_r  = lane & 15;
  const int f_p  = ((((lane >> 4) + (f_r >> 1)) & 3) << 3);

  const int lda = o.lda, ldb = o.ldb;
  const int NTILES = o.K >> 6;

  floatx4 acc[8][4] = {};

#define STAGE256(tt, g, sl)                                                     \
  do {                                                                          \
    const int mat_ = (g) & 1, h_ = (g) >> 1;                                    \
    const ushort_t* src_ = mat_ ? Bb : Ab;                                      \
    const int ld_ = mat_ ? ldb : lda;                                           \
    const int tb_ = mat_ ? tn : tm;                                             \
    const int kofs_ = (tt) * 64 + h_ * 32 + s_cg * 8;                           \
    _Pragma("unroll")                                                           \
    for (int j_ = 0; j_ < 2; j_++) {                                            \
      const int slab_ = wave * 2 + j_;                                          \
      const ushort_t* gp_ = src_ + (size_t)(tb_ + slab_ * 16 + s_r) * ld_ + kofs_; \
      load_lds16(gp_, (void*)&lds[sl][mat_][h_][slab_ * 16][0]);                \
    }                                                                           \
  } while (0)

  STAGE256(0, 0, 0);
  STAGE256(0, 1, 0);
  STAGE256(0, 2, 0);
  STAGE256(0, 3, 0);
  STAGE256(1, 0, 1);
  STAGE256(1, 1, 1);
  asm volatile("s_waitcnt vmcnt(4)" ::: "memory");
  __builtin_amdgcn_s_barrier();

  for (int t = 0; t < NTILES; t++) {
    const int sl  = t & 1;
    const int sl1 = sl ^ 1;
    const int t1  = (t + 1 < NTILES) ? t + 1 : t;
    const int t2  = (t + 2 < NTILES) ? t + 2 : t;
    s16x8 a[8], b[4];

#pragma unroll
    for (int m = 0; m < 8; m++)
      a[m] = *(const s16x8*)&lds[sl][0][0][wm * 128 + m * 16 + f_r][f_p];
#pragma unroll
    for (int n = 0; n < 4; n++)
      b[n] = *(const s16x8*)&lds[sl][1][0][wn * 64 + n * 16 + f_r][f_p];
    STAGE256(t1, 2, sl1);
    __builtin_amdgcn_s_barrier();
    __builtin_amdgcn_s_setprio(1);
#pragma unroll
    for (int m = 0; m < 8; m++)
#pragma unroll
      for (int n = 0; n < 2; n++)
        acc[m][n] = __builtin_amdgcn_mfma_f32_16x16x32_bf16(a[m], b[n], acc[m][n], 0, 0, 0);
    __builtin_amdgcn_s_setprio(0);
    __builtin_amdgcn_s_barrier();

    STAGE256(t1, 3, sl1);
    __builtin_amdgcn_s_barrier();
    __builtin_amdgcn_s_setprio(1);
#pragma unroll
    for (int m = 0; m < 8; m++)
#pragma unroll
      for (int n = 2; n < 4; n++)
        acc[m][n] = __builtin_amdgcn_mfma_f32_16x16x32_bf16(a[m], b[n], acc[m][n], 0, 0, 0);
    __builtin_amdgcn_s_setprio(0);
    __builtin_amdgcn_s_barrier();

#pragma unroll
    for (int m = 0; m < 8; m++)
      a[m] = *(const s16x8*)&lds[sl][0][1][wm * 128 + m * 16 + f_r][f_p];
#pragma unroll
    for (int n = 0; n < 4; n++)
      b[n] = *(const s16x8*)&lds[sl][1][1][wn * 64 + n * 16 + f_r][f_p];
    STAGE256(t2, 0, sl);
    __builtin_amdgcn_s_barrier();
    __builtin_amdgcn_s_setprio(1);
#pragma unroll
    for (int m = 0; m < 8; m++)
#pragma unroll
      for (int n = 0; n < 2; n++)
        acc[m][n] = __builtin_amdgcn_mfma_f32_16x16x32_bf16(a[m], b[n], acc[m][n], 0, 0, 0);
    __builtin_amdgcn_s_setprio(0);
    __builtin_amdgcn_s_barrier();

    STAGE256(t2, 1, sl);
    __builtin_amdgcn_s_barrier();
    __builtin_amdgcn_s_setprio(1);
#pragma unroll
    for (int m = 0; m < 8; m++)
#pragma unroll
      for (int n = 2; n < 4; n++)
        acc[m][n] = __builtin_amdgcn_mfma_f32_16x16x32_bf16(a[m], b[n], acc[m][n], 0, 0, 0);
    __builtin_amdgcn_s_setprio(0);
    asm volatile("s_waitcnt vmcnt(4)" ::: "memory");
    __builtin_amdgcn_s_barrier();
  }
#undef STAGE256

  const float tv = o.tau ? o.tau[bz] : 0.f;
  float*   Cp  = o.C   ? o.C   + (size_t)bz * o.sC : nullptr;
  ushort_t* Cb = o.Cbf ? o.Cbf + (size_t)bz * o.sC : nullptr;
  float bcv[4], cmv[4];
#pragma unroll
  for (int n = 0; n < 4; n++) {
    const int col = tn + wn * 64 + n * 16 + (lane & 15);
    bcv[n] = o.bias_col ? o.bias_col[col] : 0.f;
    cmv[n] = o.cmul ? o.cmul[(size_t)bz * o.cmulStride + col] : 1.f;
    if (o.flags & 4) cmv[n] = 1.f / fmaxf(sqrtf(cmv[n]), 1e-12f);
  }
#pragma unroll
  for (int m = 0; m < 8; m++) {
#pragma unroll
    for (int r = 0; r < 4; r++) {
      const int row = tm + wm * 128 + m * 16 + (lane >> 4) * 4 + r;
      float rm = o.rmul ? o.rmul[(size_t)bz * o.rmulStride + row] : 1.f;
      if (o.flags & 8) rm = 1.f / fmaxf(rm, 1e-9f);
      const float br = o.bias_row ? o.bias_row[row] : 0.f;
      float rsum = 0.f;
#pragma unroll
      for (int n = 0; n < 4; n++) {
        const int col = tn + wn * 64 + n * 16 + (lane & 15);
        float v;
        if (o.flags & 2) {
          v = acc[m][n][r] * (rm * cmv[n]) + bcv[n] + br;
        } else {
          v = (acc[m][n][r] + bcv[n] + br) * (rm * cmv[n]);
        }
        if (o.flags & 1) v = fmaxf(v, 0.f);
        if (o.tau) { float d = 1.0f - v; v = fmaxf(1.0f - tv * 0.25f * d * d, 0.f); }
        rsum += (o.rsMode == 2) ? v * v : v;
        if (Cp) Cp[(size_t)row * o.ldc + col] = v;
        if (Cb) Cb[(size_t)row * o.ldc + col] = f2b(v);
      }
      if (o.rsMode == 1 || o.rsMode == 2) {
        rsum += __shfl_xor(rsum, 1);
        rsum += __shfl_xor(rsum, 2);
        rsum += __shfl_xor(rsum, 4);
        rsum += __shfl_xor(rsum, 8);
        if ((lane & 15) == 0)
          atomicAdd(&o.rowsum[(size_t)bz * o.rsStride + row], rsum);
      }
    }
  }
}

// ---------------------------------------------------------------------------
// gemm_bt: single-op 128x128 kernel (RF, ITab, context) + XCD swizzle
// ---------------------------------------------------------------------------
__global__ __launch_bounds__(256) void gemm_bt(
    const ushort_t* __restrict__ A, const ushort_t* __restrict__ Bt,
    float* __restrict__ C, ushort_t* __restrict__ Cbf,
    const float* __restrict__ bias_col, const float* __restrict__ bias_row,
    const float* __restrict__ rmul, int rmulStride,
    const float* __restrict__ cmul, int cmulStride,
    const float* __restrict__ tau,
    float* __restrict__ rowsum, int rsStride, int rsMode,
    int K, int lda, int ldb, int ldc,
    long long sA, long long sB, long long sC, int flags)
{
  __shared__ __align__(16) ushort_t As[128 * 32];
  __shared__ __align__(16) ushort_t Bs[128 * 32];

  int bx = blockIdx.x, by = blockIdx.y, bz = blockIdx.z;
  xcd_swizzle(bx, by, bz);
  const ushort_t* Ab = A + (size_t)bz * sA;
  const ushort_t* Bb = Bt + (size_t)bz * sB;
  const int tm   = by * 128;
  const int tn   = bx * 128;
  const int tid  = threadIdx.x;
  const int wave = tid >> 6;
  const int lane = tid & 63;
  const int wm   = (wave & 1) << 6;
  const int wn   = (wave >> 1) << 6;
  const int sr   = lane >> 2;
  const int cp   = lane & 3;
  const int sc   = (((cp - (sr >> 1)) & 3) << 3);
  const int fr   = lane & 15;
  const int fk   = ((((lane >> 4) + (fr >> 1)) & 3) << 3);

  floatx4 acc[4][4] = {};

  for (int k0 = 0; k0 < K; k0 += 32) {
    {
      const ushort_t* gA0 = Ab + (size_t)(tm + wave * 16 + sr) * lda + (k0 + sc);
      const ushort_t* gA1 = gA0 + (size_t)64 * lda;
      char* lA = (char*)As + wave * 1024;
      load_lds16(gA0, lA);
      load_lds16(gA1, lA + 4096);
      const ushort_t* gB0 = Bb + (size_t)(tn + wave * 16 + sr) * ldb + (k0 + sc);
      const ushort_t* gB1 = gB0 + (size_t)64 * ldb;
      char* lB = (char*)Bs + wave * 1024;
      load_lds16(gB0, lB);
      load_lds16(gB1, lB + 4096);
    }
    __syncthreads();
    s16x8 af[4], bfv[4];
#pragma unroll
    for (int i = 0; i < 4; i++)
      af[i] = *(const s16x8*)&As[(wm + i * 16 + fr) * 32 + fk];
#pragma unroll
    for (int j = 0; j < 4; j++)
      bfv[j] = *(const s16x8*)&Bs[(wn + j * 16 + fr) * 32 + fk];
#pragma unroll
    for (int i = 0; i < 4; i++)
#pragma unroll
      for (int j = 0; j < 4; j++)
        acc[i][j] = __builtin_amdgcn_mfma_f32_16x16x32_bf16(af[i], bfv[j], acc[i][j], 0, 0, 0);
    __syncthreads();
  }

  const float tv = tau ? tau[bz] : 0.f;
  float*   Cp  = C   ? C   + (size_t)bz * sC : nullptr;
  ushort_t* Cb = Cbf ? Cbf + (size_t)bz * sC : nullptr;
  float bcv[4], cmv[4];
#pragma unroll
  for (int j = 0; j < 4; j++) {
    const int col = tn + wn + j * 16 + (lane & 15);
    bcv[j] = bias_col ? bias_col[col] : 0.f;
    cmv[j] = cmul ? cmul[(size_t)bz * cmulStride + col] : 1.f;
    if (flags & 4) cmv[j] = 1.f / fmaxf(sqrtf(cmv[j]), 1e-12f);
  }
#pragma unroll
  for (int i = 0; i < 4; i++) {
#pragma unroll
    for (int r = 0; r < 4; r++) {
      const int row = tm + wm + i * 16 + (lane >> 4) * 4 + r;
      float rm = rmul ? rmul[(size_t)bz * rmulStride + row] : 1.f;
      if (flags & 8) rm = 1.f / fmaxf(rm, 1e-9f);
      const float br = bias_row ? bias_row[row] : 0.f;
      float rsum = 0.f;
#pragma unroll
      for (int j = 0; j < 4; j++) {
        const int col = tn + wn + j * 16 + (lane & 15);
        float v;
        if (flags & 2) {
          v = acc[i][j][r] * (rm * cmv[j]) + bcv[j] + br;
        } else {
          v = (acc[i][j][r] + bcv[j] + br) * (rm * cmv[j]);
        }
        if (flags & 1) v = fmaxf(v, 0.f);
        if (tau) { float d = 1.0f - v; v = fmaxf(1.0f - tv * 0.25f * d * d, 0.f); }
        rsum += (rsMode == 2) ? v * v : v;
        if (Cp) Cp[(size_t)row * ldc + col] = v;
        if (Cb) Cb[(size_t)row * ldc + col] = f2b(v);
      }
      if (rsMode == 1 || rsMode == 2) {
        rsum += __shfl_xor(rsum, 1);
        rsum += __shfl_xor(rsum, 2);
        rsum += __shfl_xor(rsum, 4);
        rsum += __shfl_xor(rsum, 8);
        if ((lane & 15) == 0)
          atomicAdd(&rowsum[(size_t)bz * rsStride + row], rsum);
      }
    }
  }
}

// ---------------------------------------------------------------------------
// prep1: ONE launch for all independent stage-1 prep. 33408 blocks x 256 thr.
// ranges: [0,4096) gen_ftab | [.,+2048) transpose-cast Wq/Wo | [.,+2048)
// cast Wk/Wv | [.,+512) tcast Wr1 | [.,+64) tcast Wr2 | [.,+64) rolenorm |
// [.,+8192)x3 cast q/k/v inputs.
// ---------------------------------------------------------------------------
struct P1args {
  const float *Wq, *Wo, *Wk, *Wv, *Wr1, *Wr2, *roleM, *q_in, *k_in, *v_in;
  ushort_t *WqT, *WoT, *Wkb, *Wvb, *Wr1T, *Wr2T, *rmn, *FTab, *qbf, *kinb, *vinb;
};

__global__ __launch_bounds__(256) void prep1(P1args p) {
  __shared__ float t[32][33];
  __shared__ float red[6];
  int b = blockIdx.x;
  const int tid = threadIdx.x;

  if (b < 4096) {  // gen_ftab
    const float TW = 6.283185307179586f / 1024.f;
    int idx = b * 256 + tid;
    int j = idx >> 10, k = idx & 1023;
    int f = j <= 512 ? j : j - 512;
    float th = (float)((f * k) & 1023) * TW;
    float sv, cv; sincosf(th, &sv, &cv);
    p.FTab[idx] = f2b(j <= 512 ? cv : -sv);
    return;
  }
  b -= 4096;
  if (b < 2048) {  // transpose-cast 1024x1024: Wq->WqT, Wo->WoT
    const float* in = b < 1024 ? p.Wq : p.Wo;
    ushort_t* out   = b < 1024 ? p.WqT : p.WoT;
    int bb = b & 1023;
    int r0 = (bb & 31) * 32, c0 = (bb >> 5) * 32;
    int x = tid & 31, y = tid >> 5;
    for (int dy = 0; dy < 32; dy += 8)
      t[y + dy][x] = in[(size_t)(r0 + y + dy) * 1024 + c0 + x];
    __syncthreads();
    for (int dy = 0; dy < 32; dy += 8)
      out[(size_t)(c0 + y + dy) * 1024 + r0 + x] = f2b(t[x][y + dy]);
    return;
  }
  b -= 2048;
  if (b < 2048) {  // row-major cast: Wk->Wkb, Wv->Wvb
    const float* in = b < 1024 ? p.Wk : p.Wv;
    ushort_t* out   = b < 1024 ? p.Wkb : p.Wvb;
    int i = (b & 1023) * 256 + tid;
    float4 v = ((const float4*)in)[i];
    ushort4 o;
    o.x = f2b(v.x); o.y = f2b(v.y); o.z = f2b(v.z); o.w = f2b(v.w);
    ((ushort4*)out)[i] = o;
    return;
  }
  b -= 2048;
  if (b < 512) {  // tcast Wr1 (1024x512 -> 512x1024)
    int r0 = (b & 31) * 32, c0 = (b >> 5) * 32;
    int x = tid & 31, y = tid >> 5;
    for (int dy = 0; dy < 32; dy += 8)
      t[y + dy][x] = p.Wr1[(size_t)(r0 + y + dy) * 512 + c0 + x];
    __syncthreads();
    for (int dy = 0; dy < 32; dy += 8)
      p.Wr1T[(size_t)(c0 + y + dy) * 1024 + r0 + x] = f2b(t[x][y + dy]);
    return;
  }
  b -= 512;
  if (b < 64) {  // tcast Wr2 (512x64 -> 128x512, zero-padded cols >= 64)
    int r0 = (b & 15) * 32, c0 = (b >> 4) * 32;
    int x = tid & 31, y = tid >> 5;
    for (int dy = 0; dy < 32; dy += 8) {
      int r = r0 + y + dy, c = c0 + x;
      t[y + dy][x] = (c < 64) ? p.Wr2[(size_t)r * 64 + c] : 0.f;
    }
    __syncthreads();
    for (int dy = 0; dy < 32; dy += 8)
      p.Wr2T[(size_t)(c0 + y + dy) * 512 + r0 + x] = f2b(t[x][y + dy]);
    return;
  }
  b -= 64;
  if (b < 64) {  // rolenorm
    int r = b;
    float4 v = ((const float4*)(p.roleM + (size_t)r * 1024))[tid];
    float s = v.x * v.x + v.y * v.y + v.z * v.z + v.w * v.w;
#pragma unroll
    for (int m = 1; m < 64; m <<= 1) s += __shfl_xor(s, m);
    if ((tid & 63) == 0) red[tid >> 6] = s;
    __syncthreads();
    if (tid == 0) red[4] = 1.f / fmaxf(sqrtf(red[0] + red[1] + red[2] + red[3]), 1e-12f);
    __syncthreads();
    float inv = red[4];
    ushort4 o;
    o.x = f2b(v.x * inv); o.y = f2b(v.y * inv); o.z = f2b(v.z * inv); o.w = f2b(v.w * inv);
    ((ushort4*)(p.rmn + (size_t)r * 1024))[tid] = o;
    return;
  }
  b -= 64;
  {  // input casts q/k/v (8192 blocks each)
    const float* in; ushort_t* out;
    if (b < 8192)      { in = p.q_in; out = p.qbf; }
    else if (b < 16384){ in = p.k_in; out = p.kinb; b -= 8192; }
    else               { in = p.v_in; out = p.vinb; b -= 16384; }
    int i = b * 256 + tid;
    float4 v = ((const float4*)in)[i];
    ushort4 o;
    o.x = f2b(v.x); o.y = f2b(v.y); o.z = f2b(v.z); o.w = f2b(v.w);
    ((ushort4*)out)[i] = o;
  }
}

// ---------------------------------------------------------------------------
// prep2: ONE launch for stage-2 prep. 2592 blocks x 256 thr.
// ranges: [0,1024) titab | [.,+1024) rfn | [.,+256) foldbk | [.,+32)
// foldbh(parallel, atomics) | [.,+64) foldbvo(parallel) | [.,+192) prep3.
// bh/bvo must be pre-zeroed.
// ---------------------------------------------------------------------------
struct P2args {
  const ushort_t *FTab, *rmn, *Wkb, *Wvb, *WoT, *Wr1T;
  const float *bk, *br1, *bv, *bo, *Wr1, *Wo;
  ushort_t *ITab, *RFnT, *WkF, *Wov, *WkR1;
  float *bkF, *bh, *bvo;
};

__global__ __launch_bounds__(256) void prep2(P2args p) {
  __shared__ __align__(16) ushort_t As[128 * 32];
  __shared__ __align__(16) ushort_t Bs[128 * 32];
  __shared__ float t[32][33];
  int b = blockIdx.x;
  const int tid = threadIdx.x;

  if (b < 1024) {  // titab: itab[n][j] = s(j)*ftab[j][n], s pow2 -> bit-exact
    int j0 = (b & 31) * 32, n0 = (b >> 5) * 32;
    int x = tid & 31, y = tid >> 5;
    for (int dy = 0; dy < 32; dy += 8) {
      int j = j0 + y + dy;
      float s = (j == 0 || j == 512) ? (1.f / 1024.f) : (2.f / 1024.f);
      t[y + dy][x] = b2f(p.FTab[(size_t)j * 1024 + n0 + x]) * s;
    }
    __syncthreads();
    for (int dy = 0; dy < 32; dy += 8)
      p.ITab[(size_t)(n0 + y + dy) * 1024 + j0 + x] = f2b(t[x][y + dy]);
    return;
  }
  b -= 1024;
  if (b < 1024) {  // rfn: RFnT[j,r] = sum_k FTab[j,k]*rmn[r,k]
    int f = b;
    int r = tid >> 2, part = tid & 3;
    const ushort_t* fr = p.FTab + (size_t)f * 1024 + part * 256;
    const ushort_t* rr = p.rmn + (size_t)r * 1024 + part * 256;
    float s = 0.f;
#pragma unroll 4
    for (int i = 0; i < 32; i++) {
      s16x8 a = *(const s16x8*)(fr + i * 8);
      s16x8 bb = *(const s16x8*)(rr + i * 8);
#pragma unroll
      for (int j = 0; j < 8; j++) s += b2f((ushort_t)a[j]) * b2f((ushort_t)bb[j]);
    }
    s += __shfl_xor(s, 1);
    s += __shfl_xor(s, 2);
    if (part == 0) p.RFnT[(size_t)f * 128 + r] = f2b(s);
    return;
  }
  b -= 1024;
  if (b < 256) {  // foldbk: bkF[j] = sum_d FTab[j,d]*bk[d]  (4 j per block)
    int j = b * 4 + (tid >> 6);
    int lane = tid & 63;
    const ushort_t* row = p.FTab + (size_t)j * 1024 + lane * 16;
    const float* bp = p.bk + lane * 16;
    float s = 0.f;
#pragma unroll
    for (int i = 0; i < 2; i++) {
      s16x8 a = *(const s16x8*)(row + i * 8);
#pragma unroll
      for (int e = 0; e < 8; e++) s += b2f((ushort_t)a[e]) * bp[i * 8 + e];
    }
#pragma unroll
    for (int m = 1; m < 64; m <<= 1) s += __shfl_xor(s, m);
    if (lane == 0) p.bkF[j] = s;
    return;
  }
  b -= 256;
  if (b < 32) {  // foldbh parallel: bh[h] += sum_{d-slice} bk[d]*Wr1[d,h] (+br1)
    int h = (b & 1) * 256 + tid;
    int d0 = (b >> 1) * 64;
    float s = ((b >> 1) == 0) ? p.br1[h] : 0.f;
    for (int i = 0; i < 64; i++)
      s += p.bk[d0 + i] * p.Wr1[(size_t)(d0 + i) * Hh + h];
    atomicAdd(&p.bh[h], s);
    return;
  }
  b -= 32;
  if (b < 64) {  // foldbvo parallel: bvo[d] += sum_{e-slice} bv[e]*Wo[e,d] (+bo)
    int d = (b & 3) * 256 + tid;
    int e0 = (b >> 2) * 64;
    float s = ((b >> 2) == 0) ? p.bo[d] : 0.f;
    for (int i = 0; i < 64; i++)
      s += p.bv[e0 + i] * p.Wo[(size_t)(e0 + i) * 1024 + d];
    atomicAdd(&p.bvo[d], s);
    return;
  }
  b -= 64;
  {  // prep3: z=0 WkF=FTab@Wkb^T; z=1 Wov=WoT@Wvb^T; z=2 WkR1=Wr1T@Wkb^T
    const int z = b >> 6;
    const int rem = b & 63;
    const int by = rem >> 3, bx = rem & 7;
    if (z == 2 && by >= 4) return;   // M=512
    const ushort_t* Ab = (z == 0) ? p.FTab : (z == 1) ? p.WoT : p.Wr1T;
    const ushort_t* Bb = (z == 1) ? p.Wvb : p.Wkb;
    ushort_t* Cc = (z == 0) ? p.WkF : (z == 1) ? p.Wov : p.WkR1;
    const int tm = by * 128, tn = bx * 128;
    const int wave = tid >> 6, lane = tid & 63;
    const int wm = (wave & 1) << 6, wn = (wave >> 1) << 6;
    const int sr = lane >> 2, cp = lane & 3;
    const int sc = (((cp - (sr >> 1)) & 3) << 3);
    const int fr = lane & 15;
    const int fk = ((((lane >> 4) + (fr >> 1)) & 3) << 3);

    floatx4 acc[4][4] = {};
    for (int k0 = 0; k0 < Dd; k0 += 32) {
      {
        const ushort_t* gA0 = Ab + (size_t)(tm + wave * 16 + sr) * Dd + (k0 + sc);
        const ushort_t* gA1 = gA0 + (size_t)64 * Dd;
        char* lA = (char*)As + wave * 1024;
        load_lds16(gA0, lA);
        load_lds16(gA1, lA + 4096);
        const ushort_t* gB0 = Bb + (size_t)(tn + wave * 16 + sr) * Dd + (k0 + sc);
        const ushort_t* gB1 = gB0 + (size_t)64 * Dd;
        char* lB = (char*)Bs + wave * 1024;
        load_lds16(gB0, lB);
        load_lds16(gB1, lB + 4096);
      }
      __syncthreads();
      s16x8 af[4], bfv[4];
#pragma unroll
      for (int i = 0; i < 4; i++)
        af[i] = *(const s16x8*)&As[(wm + i * 16 + fr) * 32 + fk];
#pragma unroll
      for (int j = 0; j < 4; j++)
        bfv[j] = *(const s16x8*)&Bs[(wn + j * 16 + fr) * 32 + fk];
#pragma unroll
      for (int i = 0; i < 4; i++)
#pragma unroll
        for (int j = 0; j < 4; j++)
          acc[i][j] = __builtin_amdgcn_mfma_f32_16x16x32_bf16(af[i], bfv[j], acc[i][j], 0, 0, 0);
      __syncthreads();
    }
#pragma unroll
    for (int i = 0; i < 4; i++)
#pragma unroll
      for (int r = 0; r < 4; r++) {
        const int row = tm + wm + i * 16 + (lane >> 4) * 4 + r;
#pragma unroll
        for (int j = 0; j < 4; j++) {
          const int col = tn + wn + j * 16 + (lane & 15);
          Cc[(size_t)row * Dd + col] = f2b(acc[i][j][r]);
        }
      }
  }
}

// ---------------------------------------------------------------------------
// mlp2sm: fused MLP2 + softmax. One wave per row: lane o computes
// logit[o] = dot(hid[row,:], Wr2T[o,:]) over K=512 (hid staged in LDS),
// then in-wave softmax over 64 lanes -> rw bf16. grid 2048 x 256.
// ---------------------------------------------------------------------------
__global__ __launch_bounds__(256) void mlp2sm(const ushort_t* __restrict__ hid,
                                              const ushort_t* __restrict__ Wr2T,
                                              ushort_t* __restrict__ rw) {
  __shared__ __align__(16) ushort_t hrow[4][512];
  const int w = threadIdx.x >> 6, lane = threadIdx.x & 63;
  const int row = blockIdx.x * 4 + w;
  *(s16x8*)&hrow[w][lane * 8] = *(const s16x8*)&hid[(size_t)row * 512 + lane * 8];
  __syncthreads();
  const ushort_t* wrow = Wr2T + (size_t)lane * 512;
  float s = 0.f;
#pragma unroll 8
  for (int i = 0; i < 64; i++) {
    s16x8 a = *(const s16x8*)&hrow[w][i * 8];
    s16x8 bb = *(const s16x8*)&wrow[i * 8];
#pragma unroll
    for (int j = 0; j < 8; j++) s += b2f((ushort_t)a[j]) * b2f((ushort_t)bb[j]);
  }
  float m = s;
#pragma unroll
  for (int d = 1; d < 64; d <<= 1) m = fmaxf(m, __shfl_xor(m, d));
  float e = expf(s - m);
  float sum = e;
#pragma unroll
  for (int d = 1; d < 64; d <<= 1) sum += __shfl_xor(sum, d);
  rw[(size_t)row * 64 + lane] = f2b(e / sum);
}

// ---------------------------------------------------------------------------
// small kernels still standalone
// ---------------------------------------------------------------------------
__global__ __launch_bounds__(256) void invnorm_surprise(const float* __restrict__ ssq,
                                                        float* __restrict__ invn,
                                                        float* __restrict__ ssum) {
  int row = blockIdx.x * 256 + threadIdx.x;
  float nrm = sqrtf(ssq[row]);
  invn[row] = 1.f / fmaxf(nrm, 1e-12f);
  float t = nrm;
#pragma unroll
  for (int m = 1; m < 64; m <<= 1) t += __shfl_xor(t, m);
  if ((threadIdx.x & 63) == 0) atomicAdd(&ssum[row >> 11], t);
}

__global__ void finalize_astro(const float* __restrict__ ssum, const float* __restrict__ astro,
                               const float* __restrict__ ascale, float* __restrict__ tau,
                               float* __restrict__ outTail) {
  int b = threadIdx.x;
  if (b < Bq) {
    float mean = ssum[b] * (1.f / (32.f * 2048.f));
    float ns = 0.95f * astro[b] + 0.05f * mean;
    tau[b] = fmaxf(1.f + ascale[0] * ns, 0.001f);
    outTail[b] = ns;
  }
}

__global__ __launch_bounds__(256) void fftmul(const ushort_t* __restrict__ KF,
                                              const ushort_t* __restrict__ RF,
                                              ushort_t* __restrict__ P) {
  int idx = blockIdx.x * 256 + threadIdx.x;
  int t = idx >> 9;
  int j = idx & 511;
  size_t base = (size_t)t * FQ;
  if (j == 0) {
    P[base]       = f2b(b2f(KF[base]) * b2f(RF[base]));
    P[base + 512] = f2b(b2f(KF[base + 512]) * b2f(RF[base + 512]));
  } else {
    float a = b2f(KF[base + j]), b = b2f(KF[base + 512 + j]);
    float c = b2f(RF[base + j]), d = b2f(RF[base + 512 + j]);
    P[base + j]       = f2b(a * c - b * d);
    P[base + 512 + j] = f2b(a * d + b * c);
  }
}

// ---------------------------------------------------------------------------
// workspace layout (bytes, 256-aligned)
// ---------------------------------------------------------------------------
static constexpr size_t OFF_RS    = 0;
static constexpr size_t OFF_SSQQ  = 32768;
static constexpr size_t OFF_SSQK  = 65536;
static constexpr size_t OFF_INVQ  = 98304;
static constexpr size_t OFF_INVK  = 131072;
static constexpr size_t OFF_INVRS = 163840;
static constexpr size_t OFF_SSUM  = 196608;
static constexpr size_t OFF_TAU   = 196864;
static constexpr size_t OFF_WQT   = 197120;
static constexpr size_t OFF_WKB   = OFF_WQT  + 2097152;
static constexpr size_t OFF_WVB   = OFF_WKB  + 2097152;
static constexpr size_t OFF_WOT   = OFF_WVB  + 2097152;
static constexpr size_t OFF_WR1T  = OFF_WOT  + 2097152;
static constexpr size_t OFF_WR2T  = OFF_WR1T + 1048576;
static constexpr size_t OFF_RMN   = OFF_WR2T + 131072;
static constexpr size_t OFF_FTAB  = OFF_RMN  + 131072;
static constexpr size_t OFF_ITAB  = OFF_FTAB + 2097152;
static constexpr size_t OFF_RFNT  = OFF_ITAB + 2097152;
static constexpr size_t OFF_B1    = OFF_RFNT + 262144;
static constexpr size_t OFF_B2    = OFF_B1   + 16777216;
static constexpr size_t OFF_B3    = OFF_B2   + 16777216;
static constexpr size_t OFF_B4    = OFF_B3   + 16777216;
static constexpr size_t OFF_B5    = OFF_B4   + 16777216;
static constexpr size_t OFF_B6    = OFF_B5   + 16777216;
static constexpr size_t OFF_B7    = OFF_B6   + 16777216;
static constexpr size_t OFF_HID   = OFF_B7   + 16777216;
static constexpr size_t OFF_LOGI  = OFF_HID  + 8388608;
static constexpr size_t OFF_RW    = OFF_LOGI + 4194304;
static constexpr size_t OFF_SB    = OFF_RW   + 1048576;
static constexpr size_t WS_NEEDED = OFF_SB   + 33554432;
static constexpr size_t OFF_WKF   = OFF_B6;
static constexpr size_t OFF_WOV   = OFF_B6 + 2097152;
static constexpr size_t OFF_WKR1  = OFF_B6 + 4194304;
static constexpr size_t OFF_BKF   = OFF_B6 + 5242880;
static constexpr size_t OFF_BH    = OFF_B6 + 5247232;
static constexpr size_t OFF_BVO   = OFF_B6 + 5249536;

static inline void launch_gemm(hipStream_t s, const ushort_t* A, const ushort_t* Bt,
                               float* Cf, ushort_t* Cb,
                               const float* bias_col, const float* bias_row,
                               const float* rmul, int rmulStride,
                               const float* cmul, int cmulStride,
                               const float* tau, float* rowsum, int rsStride, int rsMode,
                               int M, int N, int K, int lda, int ldb, int ldc,
                               long long sA, long long sB, long long sC, int Z, int flags) {
  dim3 g(N / 128, M / 128, Z), b(256);
  gemm_bt<<<g, b, 0, s>>>(A, Bt, Cf, Cb, bias_col, bias_row, rmul, rmulStride,
                          cmul, cmulStride, tau, rowsum, rsStride, rsMode,
                          K, lda, ldb, ldc, sA, sB, sC, flags);
}

static inline GOp mkop(const ushort_t* A, const ushort_t* Bt, float* Cf, ushort_t* Cb,
                       const float* bias_col, const float* rmul, int rmulStride,
                       const float* cmul, int cmulStride, const float* tau,
                       float* rowsum, int rsStride, int rsMode,
                       int M, int N, int K, int lda, int ldb, int ldc,
                       long long sA, long long sB, long long sC, int flags,
                       int blkStart, int tile) {
  GOp o;
  o.A = A; o.Bt = Bt; o.C = Cf; o.Cbf = Cb;
  o.bias_col = bias_col; o.bias_row = nullptr;
  o.rmul = rmul; o.cmul = cmul; o.tau = tau; o.rowsum = rowsum;
  o.rmulStride = rmulStride; o.cmulStride = cmulStride;
  o.rsStride = rsStride; o.rsMode = rsMode;
  o.K = K; o.lda = lda; o.ldb = ldb; o.ldc = ldc; o.flags = flags;
  o.sA = sA; o.sB = sB; o.sC = sC;
  o.gx = N / tile; o.gy = M / tile; o.blkStart = blkStart; o.pad = 0;
  return o;
}

extern "C" void kernel_launch(void* const* d_in, const int* in_sizes, int n_in,
                              void* d_out, int out_size, void* d_ws, size_t ws_size,
                              hipStream_t stream) {
  (void)in_sizes; (void)n_in; (void)out_size;
  if (ws_size < WS_NEEDED) return;

  const float* q_in  = (const float*)d_in[0];
  const float* k_in  = (const float*)d_in[1];
  const float* v_in  = (const float*)d_in[2];
  const float* astro = (const float*)d_in[3];
  const float* Wq    = (const float*)d_in[4];
  const float* bq    = (const float*)d_in[5];
  const float* Wk    = (const float*)d_in[6];
  const float* bk    = (const float*)d_in[7];
  const float* Wv    = (const float*)d_in[8];
  const float* bv    = (const float*)d_in[9];
  const float* Wo    = (const float*)d_in[10];
  const float* bo    = (const float*)d_in[11];
  const float* roleM = (const float*)d_in[12];
  const float* Wr1   = (const float*)d_in[13];
  const float* br1   = (const float*)d_in[14];
  const float* Wr2   = (const float*)d_in[15];
  const float* ascl  = (const float*)d_in[16];

  char* ws = (char*)d_ws;
  float*    rowsumS = (float*)(ws + OFF_RS);
  float*    ssqQ    = (float*)(ws + OFF_SSQQ);
  float*    ssqK    = (float*)(ws + OFF_SSQK);
  float*    invQ    = (float*)(ws + OFF_INVQ);
  float*    ssum    = (float*)(ws + OFF_SSUM);
  float*    tau     = (float*)(ws + OFF_TAU);
  ushort_t* WqT  = (ushort_t*)(ws + OFF_WQT);
  ushort_t* Wkb  = (ushort_t*)(ws + OFF_WKB);
  ushort_t* Wvb  = (ushort_t*)(ws + OFF_WVB);
  ushort_t* WoT  = (ushort_t*)(ws + OFF_WOT);
  ushort_t* Wr1T = (ushort_t*)(ws + OFF_WR1T);
  ushort_t* Wr2T = (ushort_t*)(ws + OFF_WR2T);
  ushort_t* rmn  = (ushort_t*)(ws + OFF_RMN);
  ushort_t* FTab = (ushort_t*)(ws + OFF_FTAB);
  ushort_t* ITab = (ushort_t*)(ws + OFF_ITAB);
  ushort_t* RFnT = (ushort_t*)(ws + OFF_RFNT);
  ushort_t* qbf  = (ushort_t*)(ws + OFF_B1);   // dead after mergeA
  ushort_t* kbraw= (ushort_t*)(ws + OFF_B1);   // written by ITab GEMM
  ushort_t* kinb = (ushort_t*)(ws + OFF_B2);
  ushort_t* RF   = (ushort_t*)(ws + OFF_B2);
  ushort_t* vinb = (ushort_t*)(ws + OFF_B3);
  ushort_t* Pb   = (ushort_t*)(ws + OFF_B3);
  ushort_t* qraw = (ushort_t*)(ws + OFF_B4);
  ushort_t* KF   = (ushort_t*)(ws + OFF_B5);
  ushort_t* WkF  = (ushort_t*)(ws + OFF_WKF);
  ushort_t* Wov  = (ushort_t*)(ws + OFF_WOV);
  ushort_t* WkR1 = (ushort_t*)(ws + OFF_WKR1);
  float*    bkF  = (float*)(ws + OFF_BKF);
  float*    bh   = (float*)(ws + OFF_BH);
  float*    bvo  = (float*)(ws + OFF_BVO);
  ushort_t* vT   = (ushort_t*)(ws + OFF_B7);
  ushort_t* hid  = (ushort_t*)(ws + OFF_HID);
  ushort_t* rw   = (ushort_t*)(ws + OFF_RW);
  ushort_t* Sb   = (ushort_t*)(ws + OFF_SB);
  float*    out  = (float*)d_out;

  // 0. zero accumulators (+ bh/bvo for atomic folds)
  hipMemsetAsync(ws, 0, OFF_SSUM + 256, stream);
  hipMemsetAsync(ws + OFF_BH, 0, (OFF_BVO - OFF_BH) + 4096, stream);

  // 1. prep1: all independent stage-1 prep in one launch
  P1args p1;
  p1.Wq = Wq; p1.Wo = Wo; p1.Wk = Wk; p1.Wv = Wv; p1.Wr1 = Wr1; p1.Wr2 = Wr2;
  p1.roleM = roleM; p1.q_in = q_in; p1.k_in = k_in; p1.v_in = v_in;
  p1.WqT = WqT; p1.WoT = WoT; p1.Wkb = Wkb; p1.Wvb = Wvb; p1.Wr1T = Wr1T;
  p1.Wr2T = Wr2T; p1.rmn = rmn; p1.FTab = FTab;
  p1.qbf = qbf; p1.kinb = kinb; p1.vinb = vinb;
  prep1<<<dim3(33408), dim3(256), 0, stream>>>(p1);

  // 2. prep2: stage-2 prep (titab, rfn, folds, prep3) in one launch
  P2args p2;
  p2.FTab = FTab; p2.rmn = rmn; p2.Wkb = Wkb; p2.Wvb = Wvb; p2.WoT = WoT;
  p2.Wr1T = Wr1T; p2.bk = bk; p2.br1 = br1; p2.bv = bv; p2.bo = bo;
  p2.Wr1 = Wr1; p2.Wo = Wo;
  p2.ITab = ITab; p2.RFnT = RFnT; p2.WkF = WkF; p2.Wov = Wov; p2.WkR1 = WkR1;
  p2.bkF = bkF; p2.bh = bh; p2.bvo = bvo;
  prep2<<<dim3(2592), dim3(256), 0, stream>>>(p2);

  // 3. mergeA: {Q-proj, KF, Vw^T, MLP1} on gemm_btm (1792 blocks, 3/CU)
  {
    GB gb;
    gb.op[0] = mkop(qbf, WqT, nullptr, qraw, bq, nullptr, 0, nullptr, 0, nullptr,
                    ssqQ, 0, 2, NT, Dd, Dd, Dd, Dd, Dd, 0, 0, 0, 0, 0, 128);       // 512
    gb.op[1] = mkop(kinb, WkF, nullptr, KF, bkF, nullptr, 0, nullptr, 0, nullptr,
                    nullptr, 0, 0, NT, FQ, Dd, Dd, Dd, FQ, 0, 0, 0, 0, 512, 128);  // 512
    gb.op[2] = mkop(Wov, vinb, nullptr, vT, nullptr, nullptr, 0, nullptr, 0, nullptr,
                    nullptr, 0, 0, Dd, NT, Dd, Dd, Dd, NT, 0, 0, 0, 0, 1024, 128); // 512
    gb.op[3] = mkop(kinb, WkR1, nullptr, hid, bh, nullptr, 0, nullptr, 0, nullptr,
                    nullptr, 0, 0, NT, Hh, Dd, Dd, Dd, Hh, 0, 0, 0, 1 /*relu*/, 1536, 128); // 256
    gb.nOps = 4; gb.totBlk = 1792;
    gemm_btm<<<dim3(1792), dim3(256), 0, stream>>>(gb);
  }
  invnorm_surprise<<<NT / 256, 256, 0, stream>>>(ssqQ, invQ, ssum);
  finalize_astro<<<1, 64, 0, stream>>>(ssum, astro, ascl, tau, out + (size_t)NT * Dd);

  // 4. fused MLP2 + softmax -> rw
  mlp2sm<<<dim3(NT / 4), dim3(256), 0, stream>>>(hid, Wr2T, rw);

  // 5. RF = rw @ RFnT^T (K=64)
  launch_gemm(stream, rw, RFnT, nullptr, RF, nullptr, nullptr,
              nullptr, 0, nullptr, 0, nullptr, nullptr, 0, 0,
              NT, FQ, Rr_, Rr_, 128, FQ, 0, 0, 0, 1, 0);

  // 6. pointwise bind + inverse DFT (+sumsq -> ssqK)
  fftmul<<<(NT * 512) / 256, 256, 0, stream>>>(KF, RF, Pb);
  launch_gemm(stream, Pb, ITab, nullptr, kbraw, nullptr, nullptr,
              nullptr, 0, nullptr, 0, nullptr, ssqK, 0, 2,
              NT, Dd, FQ, FQ, FQ, Dd, 0, 0, 0, 1, 0);

  // 7. attention scores on gemm256m; cmul=ssqK with flag4 (inline rsqrt)
  {
    GB gb;
    GOp o = mkop(qraw, kbraw, nullptr, Sb, nullptr, invQ, Tq, ssqK, Tq, tau,
                 rowsumS, Tq, 1, Tq, Tq, Dd, Dd, Dd, Tq,
                 (long long)Tq * Dd, (long long)Tq * Dd, (long long)Tq * Tq,
                 4 /*cmul=ssq*/, 0, 256);
    gb.op[0] = o; gb.op[1] = o; gb.op[2] = o; gb.op[3] = o;
    gb.nOps = 1; gb.totBlk = 256;
    gemm256m<<<dim3(256), dim3(512), 0, stream>>>(gb);
  }

  // 8. context -> out; rmul=rowsumS with flag8 (inline reciprocal)
  launch_gemm(stream, Sb, vT, out, nullptr, bvo, nullptr,
              rowsumS, Tq, nullptr, 0, nullptr, nullptr, 0, 0,
              Tq, Dd, Tq, Tq, NT, Dd,
              (long long)Tq * Tq, (long long)Tq, (long long)Tq * Dd, Bq,
              2 | 8 /*scale-then-bias, rmul=rowsum*/);
}